// Round 1
// baseline (1783.324 us; speedup 1.0000x reference)
//
#include <hip/hip_runtime.h>
#include <math.h>

// ---------------- problem constants ----------------
#define BB   64
#define HH   128
#define WW   128
#define GG   16
#define NN   256     // G*G tokens
#define EE   256
#define FD   320
#define NSL  8       // slots
#define NHEAD 4
#define HD   64
#define KIM  768     // 12*8*8 im2col K

__device__ __forceinline__ float sigm(float x) { return 1.0f / (1.0f + expf(-x)); }
__device__ __forceinline__ float gelu_exact(float x) {
    return 0.5f * x * (1.0f + erff(x * 0.70710678118654752f));
}

// ---------------- Sobel + one-hot + im2col ----------------
// X0[row=b*256+gy*16+gx][k=c*64+i*8+j], c: 0..9 onehot, 10 sx, 11 sy
__global__ __launch_bounds__(256) void sobel_im2col(const float* __restrict__ state,
                                                    float* __restrict__ X0) {
    int idx = blockIdx.x * 256 + threadIdx.x;
    if (idx >= BB * HH * WW) return;
    int w = idx % WW;
    int h = (idx / WW) % HH;
    int b = idx / (HH * WW);
    const float* st = state + (long)b * HH * WW;
    auto at = [&](int y, int x) {
        y = min(max(y, 0), HH - 1);
        x = min(max(x, 0), WW - 1);
        return st[y * WW + x];
    };
    float v00 = at(h-1, w-1), v01 = at(h-1, w), v02 = at(h-1, w+1);
    float v10 = at(h,   w-1),                  v12 = at(h,   w+1);
    float v20 = at(h+1, w-1), v21 = at(h+1, w), v22 = at(h+1, w+1);
    float sx = (v02 - v00) + 2.0f * (v12 - v10) + (v22 - v20);
    float sy = (v20 - v00) + 2.0f * (v21 - v01) + (v22 - v02);
    int id = (int)st[h * WW + w];
    int gy = h >> 3, i = h & 7, gx = w >> 3, j = w & 7;
    long row = (long)b * NN + gy * GG + gx;
    float* xr = X0 + row * KIM + i * 8 + j;
#pragma unroll
    for (int c = 0; c < 10; c++) xr[c * 64] = (id == c) ? 1.0f : 0.0f;
    xr[10 * 64] = sx;
    xr[11 * 64] = sy;
}

// ---------------- generic batched NT GEMM ----------------
// C[m][n] = act(scale * sum_k A[m][k]*W[n][k] + bias[n]) (+ res)
// Requires M%64==0, N%64==0, K%16==0.
template <int ACT>
__global__ __launch_bounds__(256) void gemm_nt(
    const float* __restrict__ A, const float* __restrict__ W,
    const float* __restrict__ bias, const float* __restrict__ res,
    float* __restrict__ C, int M, int N, int K,
    long sA, long sW, long sC1, long sC2, int cdiv, int ldc, float scale)
{
    const int bz = blockIdx.z;
    const float* Ab = A + (long)bz * sA;
    const float* Wb = W + (long)bz * sW;
    const long offC = (long)(bz / cdiv) * sC1 + (long)(bz % cdiv) * sC2;
    float* Cb = C + offC;
    const float* Rb = res ? res + offC : nullptr;

    __shared__ float As[16][68];
    __shared__ float Ws[16][68];

    const int tid = threadIdx.x;
    const int tx = tid & 15;
    const int ty = tid >> 4;
    const int row0 = blockIdx.y << 6;
    const int col0 = blockIdx.x << 6;

    float acc[4][4] = {};

    for (int k0 = 0; k0 < K; k0 += 16) {
#pragma unroll
        for (int i = 0; i < 4; i++) {
            const int idx = tid + (i << 8);
            const int m = idx >> 4;
            const int kk = idx & 15;
            As[kk][m] = Ab[(long)(row0 + m) * K + (k0 + kk)];
            Ws[kk][m] = Wb[(long)(col0 + m) * K + (k0 + kk)];
        }
        __syncthreads();
#pragma unroll
        for (int kk = 0; kk < 16; kk++) {
            const float4 a4 = *(const float4*)&As[kk][ty << 2];
            const float4 b4 = *(const float4*)&Ws[kk][tx << 2];
            const float a[4] = {a4.x, a4.y, a4.z, a4.w};
            const float b[4] = {b4.x, b4.y, b4.z, b4.w};
#pragma unroll
            for (int i = 0; i < 4; i++)
#pragma unroll
                for (int j = 0; j < 4; j++)
                    acc[i][j] = fmaf(a[i], b[j], acc[i][j]);
        }
        __syncthreads();
    }

    const int crow = row0 + (ty << 2);
    const int ccol = col0 + (tx << 2);
#pragma unroll
    for (int i = 0; i < 4; i++) {
#pragma unroll
        for (int j = 0; j < 4; j++) {
            float v = acc[i][j] * scale;
            if (bias) v += bias[ccol + j];
            if (ACT == 1) v = gelu_exact(v);
            if (Rb) v += Rb[(long)(crow + i) * ldc + (ccol + j)];
            Cb[(long)(crow + i) * ldc + (ccol + j)] = v;
        }
    }
}

// ---------------- LayerNorm (wave per row, two-pass) ----------------
__global__ __launch_bounds__(256) void ln_rows(const float* __restrict__ X,
                                               float* __restrict__ Y,
                                               const float* __restrict__ g,
                                               const float* __restrict__ b,
                                               int rows, int D) {
    int gtid = blockIdx.x * 256 + threadIdx.x;
    int row = gtid >> 6;
    int lane = gtid & 63;
    if (row >= rows) return;
    const float* x = X + (long)row * D;
    const int nv = D >> 6;  // D multiple of 64, <= 320
    float v[5];
    float s = 0.0f;
#pragma unroll 5
    for (int i = 0; i < nv; i++) { v[i] = x[lane + (i << 6)]; s += v[i]; }
#pragma unroll
    for (int o = 32; o; o >>= 1) s += __shfl_down(s, o);
    s = __shfl(s, 0);
    float mean = s / (float)D;
    float s2 = 0.0f;
#pragma unroll 5
    for (int i = 0; i < nv; i++) { float d = v[i] - mean; s2 += d * d; }
#pragma unroll
    for (int o = 32; o; o >>= 1) s2 += __shfl_down(s2, o);
    s2 = __shfl(s2, 0);
    float inv = rsqrtf(s2 / (float)D + 1e-5f);
    float* y = Y + (long)row * D;
#pragma unroll 5
    for (int i = 0; i < nv; i++) {
        int d = lane + (i << 6);
        y[d] = (v[i] - mean) * inv * g[d] + b[d];
    }
}

// ---------------- RoPE + head split ----------------
// QKV (16384 x 768) -> Qr,Kr (bh, n, d), Vt (bh, d, n)
__global__ __launch_bounds__(256) void rope_split(const float* __restrict__ QKV,
                                                  float* __restrict__ Qr,
                                                  float* __restrict__ Kr,
                                                  float* __restrict__ Vt) {
    int idx = blockIdx.x * 256 + threadIdx.x;  // B*N*NHEAD*HD
    if (idx >= BB * NN * NHEAD * HD) return;
    int d = idx & 63;
    int h = (idx >> 6) & 3;
    int n = (idx >> 8) & 255;
    int b = idx >> 16;
    long row = (long)b * NN + n;
    const float* base = QKV + row * 768 + h * 64;

    // rope tables inline: pos = y for d<32 else x; j = d&31
    int pos = (d < 32) ? (n >> 4) : (n & 15);
    int j = d & 31;
    float ang;
    if (j < 16) ang = sinf((float)pos * powf(10000.0f, -(float)j / 16.0f));
    else        ang = cosf((float)pos * powf(10000.0f, -(float)(j - 16) / 16.0f));
    float cv = cosf(ang), sv = sinf(ang);

    float xq = base[d];
    float rq = (d < 32) ? -base[2 * d + 1] : base[2 * (d - 32)];
    float xk = base[256 + d];
    float rk = (d < 32) ? -base[256 + 2 * d + 1] : base[256 + 2 * (d - 32)];

    long bh = (long)b * NHEAD + h;
    Qr[bh * (NN * HD) + (long)n * HD + d] = xq * cv + rq * sv;
    Kr[bh * (NN * HD) + (long)n * HD + d] = xk * cv + rk * sv;
    Vt[bh * (NN * HD) + (long)d * NN + n] = base[512 + d];
}

// ---------------- attention softmax (wave per 256-row) ----------------
__global__ __launch_bounds__(256) void softmax256(float* __restrict__ S, int rows) {
    int gtid = blockIdx.x * 256 + threadIdx.x;
    int row = gtid >> 6;
    int lane = gtid & 63;
    if (row >= rows) return;
    float* r = S + (long)row * 256;
    float v[4];
    float m = -1e30f;
#pragma unroll
    for (int i = 0; i < 4; i++) { v[i] = r[lane + (i << 6)]; m = fmaxf(m, v[i]); }
#pragma unroll
    for (int o = 32; o; o >>= 1) m = fmaxf(m, __shfl_down(m, o));
    m = __shfl(m, 0);
    float s = 0.0f;
#pragma unroll
    for (int i = 0; i < 4; i++) { v[i] = expf(v[i] - m); s += v[i]; }
#pragma unroll
    for (int o = 32; o; o >>= 1) s += __shfl_down(s, o);
    s = __shfl(s, 0);
    float inv = 1.0f / s;
#pragma unroll
    for (int i = 0; i < 4; i++) r[lane + (i << 6)] = v[i] * inv;
}

// ---------------- slot logits + softmax over slots ----------------
// sattn[b][n][s], sums[b][s] = sum_n sattn + 256e-8
__global__ __launch_bounds__(256) void slot_logits(const float* __restrict__ Kin,
                                                   const float* __restrict__ Qs,
                                                   float* __restrict__ sattn,
                                                   float* __restrict__ sums) {
    int b = blockIdx.x;
    __shared__ float qs[NSL][FD];
    __shared__ float colsum[NSL];
    int tid = threadIdx.x;
    for (int i = tid; i < NSL * FD; i += 256) qs[i / FD][i % FD] = Qs[(long)b * NSL * FD + i];
    if (tid < NSL) colsum[tid] = 0.0f;
    __syncthreads();
    int wv = tid >> 6, lane = tid & 63;
    for (int r = wv; r < NN; r += 4) {
        const float* kr = Kin + ((long)b * NN + r) * FD;
        float acc[NSL] = {};
        for (int t = lane; t < FD; t += 64) {
            float kv = kr[t];
#pragma unroll
            for (int s = 0; s < NSL; s++) acc[s] = fmaf(kv, qs[s][t], acc[s]);
        }
#pragma unroll
        for (int s = 0; s < NSL; s++)
#pragma unroll
            for (int o = 32; o; o >>= 1) acc[s] += __shfl_down(acc[s], o);
        if (lane == 0) {
            const float scale = 0.055901699437494740f;  // 1/sqrt(320)
            float mx = -1e30f;
#pragma unroll
            for (int s = 0; s < NSL; s++) { acc[s] *= scale; mx = fmaxf(mx, acc[s]); }
            float e[NSL], sum = 0.0f;
#pragma unroll
            for (int s = 0; s < NSL; s++) { e[s] = expf(acc[s] - mx); sum += e[s]; }
            float rs = 1.0f / sum;
            float* out = sattn + ((long)b * NN + r) * NSL;
#pragma unroll
            for (int s = 0; s < NSL; s++) {
                float p = e[s] * rs;
                out[s] = p;
                atomicAdd(&colsum[s], p);
            }
        }
    }
    __syncthreads();
    if (tid < NSL) sums[b * NSL + tid] = colsum[tid] + (float)NN * 1e-8f;
}

// ---------------- slot updates: updates[b][s][f] = sum_n an[n][s]*v_in[n][f] ----------------
__global__ __launch_bounds__(256) void slot_updates(const float* __restrict__ sattn,
                                                    const float* __restrict__ sums,
                                                    const float* __restrict__ Vin,
                                                    float* __restrict__ Upd) {
    int b = blockIdx.x;
    int t = threadIdx.x;
    __shared__ float an[NN][NSL];
    __shared__ float inv_s[NSL];
    if (t < NSL) inv_s[t] = 1.0f / sums[b * NSL + t];
    __syncthreads();
    for (int i = t; i < NN * NSL; i += 256) {
        int s = i & 7;
        an[i >> 3][s] = (sattn[(long)b * NN * NSL + i] + 1e-8f) * inv_s[s];
    }
    __syncthreads();
    float acc[NSL][2] = {};
    const float* vb = Vin + (long)b * NN * FD;
    for (int n = 0; n < NN; n++) {
        float v1 = vb[(long)n * FD + t];
        float v2 = (t < 64) ? vb[(long)n * FD + 256 + t] : 0.0f;
#pragma unroll
        for (int s = 0; s < NSL; s++) {
            float a = an[n][s];
            acc[s][0] = fmaf(a, v1, acc[s][0]);
            acc[s][1] = fmaf(a, v2, acc[s][1]);
        }
    }
    float* ub = Upd + (long)b * NSL * FD;
#pragma unroll
    for (int s = 0; s < NSL; s++) {
        ub[s * FD + t] = acc[s][0];
        if (t < 64) ub[s * FD + 256 + t] = acc[s][1];
    }
}

// ---------------- GRU elementwise combine ----------------
__global__ __launch_bounds__(256) void gru_elem(const float* __restrict__ GI,
                                                const float* __restrict__ GH,
                                                float* __restrict__ slots) {
    int idx = blockIdx.x * 256 + threadIdx.x;
    if (idx >= BB * NSL * FD) return;
    int r = idx / FD, f = idx % FD;
    const float* gi = GI + (long)r * 3 * FD;
    const float* gh = GH + (long)r * 3 * FD;
    float rr = sigm(gi[f] + gh[f]);
    float z = sigm(gi[FD + f] + gh[FD + f]);
    float nn = tanhf(gi[2 * FD + f] + rr * gh[2 * FD + f]);
    float h = slots[idx];
    slots[idx] = (1.0f - z) * nn + z * h;
}

// ---------------- output packing ----------------
__global__ __launch_bounds__(256) void write_out(const float* __restrict__ slots,
                                                 const float* __restrict__ sattn,
                                                 float* __restrict__ out) {
    int idx = blockIdx.x * 256 + threadIdx.x;
    const int SLOT_SZ = BB * NSL * FD;      // 163840
    const int MASK_SZ = BB * NSL * NN;      // 131072
    if (idx < SLOT_SZ) {
        out[idx] = slots[idx];
    } else if (idx < SLOT_SZ + MASK_SZ) {
        int i = idx - SLOT_SZ;
        int b = i >> 11;            // / (NSL*NN)
        int s = (i >> 8) & 7;
        int n = i & 255;
        out[idx] = sattn[((long)b * NN + n) * NSL + s];
    }
}

// ---------------- host launcher ----------------
extern "C" void kernel_launch(void* const* d_in, const int* in_sizes, int n_in,
                              void* d_out, int out_size, void* d_ws, size_t ws_size,
                              hipStream_t stream) {
    const float* state    = (const float*)d_in[0];
    const float* conv_w   = (const float*)d_in[1];
    const float* conv_b   = (const float*)d_in[2];
    const float* mlp_ln_g = (const float*)d_in[3];
    const float* mlp_ln_b = (const float*)d_in[4];
    const float* mlp_w1   = (const float*)d_in[5];
    const float* mlp_b1   = (const float*)d_in[6];
    const float* mlp_w2   = (const float*)d_in[7];
    const float* mlp_b2   = (const float*)d_in[8];
    const float* qkv_w    = (const float*)d_in[9];
    const float* qkv_b    = (const float*)d_in[10];
    const float* proj_w   = (const float*)d_in[11];
    const float* proj_b   = (const float*)d_in[12];
    const float* ni_g     = (const float*)d_in[13];
    const float* ni_b     = (const float*)d_in[14];
    const float* ns_g     = (const float*)d_in[15];
    const float* ns_b     = (const float*)d_in[16];
    const float* nm_g     = (const float*)d_in[17];
    const float* nm_b     = (const float*)d_in[18];
    const float* q_w      = (const float*)d_in[19];
    const float* k_w      = (const float*)d_in[20];
    const float* v_w      = (const float*)d_in[21];
    const float* gru_wih  = (const float*)d_in[22];
    const float* gru_whh  = (const float*)d_in[23];
    const float* gru_bih  = (const float*)d_in[24];
    const float* gru_bhh  = (const float*)d_in[25];
    const float* smlp_w1  = (const float*)d_in[26];
    const float* smlp_b1  = (const float*)d_in[27];
    const float* smlp_w2  = (const float*)d_in[28];
    const float* smlp_b2  = (const float*)d_in[29];

    float* ws = (float*)d_ws;
    const int M = BB * NN;  // 16384

    // workspace layout (floats), with lifetime-based reuse
    float* X0   = ws + 0L;            // 12.6M -> later QKV -> later S (16.78M region)
    float* QKV  = X0;
    float* S    = X0;
    float* X1   = ws + 16777216L;     // 4.19M -> later AO
    float* AO   = X1;
    float* XLN  = ws + 20971520L;     // 4.19M -> later Vt
    float* Vt   = XLN;
    float* Hbuf = ws + 25165824L;     // 8.39M -> later Qr+Kr
    float* Qr   = Hbuf;
    float* Kr   = Hbuf + 4194304L;
    float* X2   = ws + 33554432L;     // live until proj residual -> later Xn
    float* Xn   = X2;
    float* X3   = ws + 37748736L;
    float* Kin  = ws + 41943040L;     // 5.24M
    float* Vin  = ws + 47185920L;     // 5.24M
    float* Slots= ws + 52428800L;     // 163840
    float* SLn  = ws + 52592640L;     // 163840
    float* Qs   = ws + 52756480L;     // 163840
    float* Satt = ws + 52920320L;     // 131072
    float* Sums = ws + 53051392L;     // 512
    float* Upd  = ws + 53051904L;     // 163840
    float* GI   = ws + 53215744L;     // 491520
    float* GH   = ws + 53707264L;     // 491520
    float* Mh   = ws + 54198784L;     // 327680

    float* out = (float*)d_out;

    auto gemm = [&](const float* A, const float* W, const float* bias, const float* res,
                    float* C, int Mm, int Nn, int Kk, int batch,
                    long sA, long sW, long sC1, long sC2, int cdiv, int ldc,
                    float scale, int act) {
        dim3 grid(Nn / 64, Mm / 64, batch);
        if (act)
            gemm_nt<1><<<grid, 256, 0, stream>>>(A, W, bias, res, C, Mm, Nn, Kk,
                                                 sA, sW, sC1, sC2, cdiv, ldc, scale);
        else
            gemm_nt<0><<<grid, 256, 0, stream>>>(A, W, bias, res, C, Mm, Nn, Kk,
                                                 sA, sW, sC1, sC2, cdiv, ldc, scale);
    };

    // 1. sobel + onehot + im2col
    sobel_im2col<<<dim3((BB * HH * WW) / 256), 256, 0, stream>>>(state, X0);
    // 2. patch conv as GEMM
    gemm(X0, conv_w, conv_b, nullptr, X1, M, EE, KIM, 1, 0, 0, 0, 0, 1, EE, 1.0f, 0);
    // 3. LN + MLP
    ln_rows<<<dim3(M * 64 / 256), 256, 0, stream>>>(X1, XLN, mlp_ln_g, mlp_ln_b, M, EE);
    gemm(XLN, mlp_w1, mlp_b1, nullptr, Hbuf, M, 2 * EE, EE, 1, 0, 0, 0, 0, 1, 2 * EE, 1.0f, 1);
    gemm(Hbuf, mlp_w2, mlp_b2, nullptr, X2, M, EE, 2 * EE, 1, 0, 0, 0, 0, 1, EE, 1.0f, 0);
    // 4. QKV + RoPE
    gemm(X2, qkv_w, qkv_b, nullptr, QKV, M, 3 * EE, EE, 1, 0, 0, 0, 0, 1, 3 * EE, 1.0f, 0);
    rope_split<<<dim3((BB * NN * NHEAD * HD) / 256), 256, 0, stream>>>(QKV, Qr, Kr, Vt);
    // 5. attention: S = Q K^T * 0.125 ; softmax ; AO = P V
    gemm(Qr, Kr, nullptr, nullptr, S, NN, NN, HD, BB * NHEAD,
         (long)NN * HD, (long)NN * HD, (long)NN * NN, 0, 1, NN, 0.125f, 0);
    softmax256<<<dim3(BB * NHEAD * NN * 64 / 256), 256, 0, stream>>>(S, BB * NHEAD * NN);
    gemm(S, Vt, nullptr, nullptr, AO, NN, HD, NN, BB * NHEAD,
         (long)NN * NN, (long)NN * HD, (long)NN * EE, HD, NHEAD, EE, 1.0f, 0);
    // 6. proj + residual
    gemm(AO, proj_w, proj_b, X2, X3, M, EE, EE, 1, 0, 0, 0, 0, 1, EE, 1.0f, 0);
    // 7. LN ni, k_in, v_in
    ln_rows<<<dim3(M * 64 / 256), 256, 0, stream>>>(X3, Xn, ni_g, ni_b, M, EE);
    gemm(Xn, k_w, nullptr, nullptr, Kin, M, FD, EE, 1, 0, 0, 0, 0, 1, FD, 1.0f, 0);
    gemm(Xn, v_w, nullptr, nullptr, Vin, M, FD, EE, 1, 0, 0, 0, 0, 1, FD, 1.0f, 0);
    // 8. slot attention loop
    hipMemsetAsync(Slots, 0, (size_t)BB * NSL * FD * sizeof(float), stream);
    const int SR = BB * NSL;  // 512 slot rows
    for (int it = 0; it < 3; it++) {
        ln_rows<<<dim3(SR * 64 / 256), 256, 0, stream>>>(Slots, SLn, ns_g, ns_b, SR, FD);
        gemm(SLn, q_w, nullptr, nullptr, Qs, SR, FD, FD, 1, 0, 0, 0, 0, 1, FD, 1.0f, 0);
        slot_logits<<<dim3(BB), 256, 0, stream>>>(Kin, Qs, Satt, Sums);
        slot_updates<<<dim3(BB), 256, 0, stream>>>(Satt, Sums, Vin, Upd);
        gemm(Upd, gru_wih, gru_bih, nullptr, GI, SR, 3 * FD, FD, 1, 0, 0, 0, 0, 1, 3 * FD, 1.0f, 0);
        gemm(Slots, gru_whh, gru_bhh, nullptr, GH, SR, 3 * FD, FD, 1, 0, 0, 0, 0, 1, 3 * FD, 1.0f, 0);
        gru_elem<<<dim3((SR * FD) / 256), 256, 0, stream>>>(GI, GH, Slots);
        ln_rows<<<dim3(SR * 64 / 256), 256, 0, stream>>>(Slots, SLn, nm_g, nm_b, SR, FD);
        gemm(SLn, smlp_w1, smlp_b1, nullptr, Mh, SR, 2 * FD, FD, 1, 0, 0, 0, 0, 1, 2 * FD, 1.0f, 1);
        gemm(Mh, smlp_w2, smlp_b2, Slots, Slots, SR, FD, 2 * FD, 1, 0, 0, 0, 0, 1, FD, 1.0f, 0);
    }
    // 9. outputs
    write_out<<<dim3((BB * NSL * FD + BB * NSL * NN + 255) / 256), 256, 0, stream>>>(Slots, Satt, out);
}

// Round 2
// 1309.323 us; speedup vs baseline: 1.3620x; 1.3620x over previous
//
#include <hip/hip_runtime.h>
#include <math.h>

// ---------------- problem constants ----------------
#define BB   64
#define HH   128
#define WW   128
#define GG   16
#define NN   256     // G*G tokens
#define EE   256
#define FD   320
#define NSL  8       // slots
#define NHEAD 4
#define HD   64
#define KIM  768     // 12*8*8 im2col K

__device__ __forceinline__ float sigm(float x) { return 1.0f / (1.0f + expf(-x)); }
__device__ __forceinline__ float gelu_exact(float x) {
    return 0.5f * x * (1.0f + erff(x * 0.70710678118654752f));
}

// ---------------- Sobel + one-hot + im2col ----------------
// X0[row=b*256+gy*16+gx][k=c*64+i*8+j], c: 0..9 onehot, 10 sx, 11 sy
__global__ __launch_bounds__(256) void sobel_im2col(const float* __restrict__ state,
                                                    float* __restrict__ X0) {
    int idx = blockIdx.x * 256 + threadIdx.x;
    if (idx >= BB * HH * WW) return;
    int w = idx % WW;
    int h = (idx / WW) % HH;
    int b = idx / (HH * WW);
    const float* st = state + (long)b * HH * WW;
    auto at = [&](int y, int x) {
        y = min(max(y, 0), HH - 1);
        x = min(max(x, 0), WW - 1);
        return st[y * WW + x];
    };
    float v00 = at(h-1, w-1), v01 = at(h-1, w), v02 = at(h-1, w+1);
    float v10 = at(h,   w-1),                  v12 = at(h,   w+1);
    float v20 = at(h+1, w-1), v21 = at(h+1, w), v22 = at(h+1, w+1);
    float sx = (v02 - v00) + 2.0f * (v12 - v10) + (v22 - v20);
    float sy = (v20 - v00) + 2.0f * (v21 - v01) + (v22 - v02);
    int id = (int)st[h * WW + w];
    int gy = h >> 3, i = h & 7, gx = w >> 3, j = w & 7;
    long row = (long)b * NN + gy * GG + gx;
    float* xr = X0 + row * KIM + i * 8 + j;
#pragma unroll
    for (int c = 0; c < 10; c++) xr[c * 64] = (id == c) ? 1.0f : 0.0f;
    xr[10 * 64] = sx;
    xr[11 * 64] = sy;
}

// ---------------- generic batched NT GEMM ----------------
// C[m][n] = act(scale * sum_k A[m][k]*W[n][k] + bias[n]) (+ res)
// Requires M%64==0, N%64==0, K%16==0.
template <int ACT>
__global__ __launch_bounds__(256) void gemm_nt(
    const float* __restrict__ A, const float* __restrict__ W,
    const float* __restrict__ bias, const float* __restrict__ res,
    float* __restrict__ C, int M, int N, int K,
    long sA, long sW, long sC1, long sC2, int cdiv, int ldc, float scale)
{
    const int bz = blockIdx.z;
    const float* Ab = A + (long)bz * sA;
    const float* Wb = W + (long)bz * sW;
    const long offC = (long)(bz / cdiv) * sC1 + (long)(bz % cdiv) * sC2;
    float* Cb = C + offC;
    const float* Rb = res ? res + offC : nullptr;

    __shared__ float As[16][68];
    __shared__ float Ws[16][68];

    const int tid = threadIdx.x;
    const int tx = tid & 15;
    const int ty = tid >> 4;
    const int row0 = blockIdx.y << 6;
    const int col0 = blockIdx.x << 6;

    float acc[4][4] = {};

    for (int k0 = 0; k0 < K; k0 += 16) {
#pragma unroll
        for (int i = 0; i < 4; i++) {
            const int idx = tid + (i << 8);
            const int m = idx >> 4;
            const int kk = idx & 15;
            As[kk][m] = Ab[(long)(row0 + m) * K + (k0 + kk)];
            Ws[kk][m] = Wb[(long)(col0 + m) * K + (k0 + kk)];
        }
        __syncthreads();
#pragma unroll
        for (int kk = 0; kk < 16; kk++) {
            const float4 a4 = *(const float4*)&As[kk][ty << 2];
            const float4 b4 = *(const float4*)&Ws[kk][tx << 2];
            const float a[4] = {a4.x, a4.y, a4.z, a4.w};
            const float b[4] = {b4.x, b4.y, b4.z, b4.w};
#pragma unroll
            for (int i = 0; i < 4; i++)
#pragma unroll
                for (int j = 0; j < 4; j++)
                    acc[i][j] = fmaf(a[i], b[j], acc[i][j]);
        }
        __syncthreads();
    }

    const int crow = row0 + (ty << 2);
    const int ccol = col0 + (tx << 2);
#pragma unroll
    for (int i = 0; i < 4; i++) {
#pragma unroll
        for (int j = 0; j < 4; j++) {
            float v = acc[i][j] * scale;
            if (bias) v += bias[ccol + j];
            if (ACT == 1) v = gelu_exact(v);
            if (Rb) v += Rb[(long)(crow + i) * ldc + (ccol + j)];
            Cb[(long)(crow + i) * ldc + (ccol + j)] = v;
        }
    }
}

// ---------------- LayerNorm (wave per row, two-pass) ----------------
__global__ __launch_bounds__(256) void ln_rows(const float* __restrict__ X,
                                               float* __restrict__ Y,
                                               const float* __restrict__ g,
                                               const float* __restrict__ b,
                                               int rows, int D) {
    int gtid = blockIdx.x * 256 + threadIdx.x;
    int row = gtid >> 6;
    int lane = gtid & 63;
    if (row >= rows) return;
    const float* x = X + (long)row * D;
    const int nv = D >> 6;  // D multiple of 64, <= 320
    float v[5];
    float s = 0.0f;
#pragma unroll 5
    for (int i = 0; i < nv; i++) { v[i] = x[lane + (i << 6)]; s += v[i]; }
#pragma unroll
    for (int o = 32; o; o >>= 1) s += __shfl_down(s, o);
    s = __shfl(s, 0);
    float mean = s / (float)D;
    float s2 = 0.0f;
#pragma unroll 5
    for (int i = 0; i < nv; i++) { float d = v[i] - mean; s2 += d * d; }
#pragma unroll
    for (int o = 32; o; o >>= 1) s2 += __shfl_down(s2, o);
    s2 = __shfl(s2, 0);
    float inv = rsqrtf(s2 / (float)D + 1e-5f);
    float* y = Y + (long)row * D;
#pragma unroll 5
    for (int i = 0; i < nv; i++) {
        int d = lane + (i << 6);
        y[d] = (v[i] - mean) * inv * g[d] + b[d];
    }
}

// ---------------- RoPE + head split ----------------
// QKV (16384 x 768) -> Qr,Kr (bh, n, d), Vt (bh, d, n)
__global__ __launch_bounds__(256) void rope_split(const float* __restrict__ QKV,
                                                  float* __restrict__ Qr,
                                                  float* __restrict__ Kr,
                                                  float* __restrict__ Vt) {
    int idx = blockIdx.x * 256 + threadIdx.x;  // B*N*NHEAD*HD
    if (idx >= BB * NN * NHEAD * HD) return;
    int d = idx & 63;
    int h = (idx >> 6) & 3;
    int n = (idx >> 8) & 255;
    int b = idx >> 16;
    long row = (long)b * NN + n;
    const float* base = QKV + row * 768 + h * 64;

    // rope tables inline: pos = y for d<32 else x; j = d&31
    int pos = (d < 32) ? (n >> 4) : (n & 15);
    int j = d & 31;
    float ang;
    if (j < 16) ang = sinf((float)pos * powf(10000.0f, -(float)j / 16.0f));
    else        ang = cosf((float)pos * powf(10000.0f, -(float)(j - 16) / 16.0f));
    float cv = cosf(ang), sv = sinf(ang);

    float xq = base[d];
    float rq = (d < 32) ? -base[2 * d + 1] : base[2 * (d - 32)];
    float xk = base[256 + d];
    float rk = (d < 32) ? -base[256 + 2 * d + 1] : base[256 + 2 * (d - 32)];

    long bh = (long)b * NHEAD + h;
    Qr[bh * (NN * HD) + (long)n * HD + d] = xq * cv + rq * sv;
    Kr[bh * (NN * HD) + (long)n * HD + d] = xk * cv + rk * sv;
    Vt[bh * (NN * HD) + (long)d * NN + n] = base[512 + d];
}

// ---------------- attention softmax (wave per 256-row) ----------------
__global__ __launch_bounds__(256) void softmax256(float* __restrict__ S, int rows) {
    int gtid = blockIdx.x * 256 + threadIdx.x;
    int row = gtid >> 6;
    int lane = gtid & 63;
    if (row >= rows) return;
    float* r = S + (long)row * 256;
    float v[4];
    float m = -1e30f;
#pragma unroll
    for (int i = 0; i < 4; i++) { v[i] = r[lane + (i << 6)]; m = fmaxf(m, v[i]); }
#pragma unroll
    for (int o = 32; o; o >>= 1) m = fmaxf(m, __shfl_down(m, o));
    m = __shfl(m, 0);
    float s = 0.0f;
#pragma unroll
    for (int i = 0; i < 4; i++) { v[i] = expf(v[i] - m); s += v[i]; }
#pragma unroll
    for (int o = 32; o; o >>= 1) s += __shfl_down(s, o);
    s = __shfl(s, 0);
    float inv = 1.0f / s;
#pragma unroll
    for (int i = 0; i < 4; i++) r[lane + (i << 6)] = v[i] * inv;
}

// ---------------- slot logits + softmax over slots (high occupancy) ----------------
// grid (BB, 16): each block does 16 rows; 4 waves x 4 rows.
// sattn[b][n][s] = softmax_s(logits); Sums[b][s] += sum_n sattn (raw, no eps)
__global__ __launch_bounds__(256) void slot_logits(const float* __restrict__ Kin,
                                                   const float* __restrict__ Qs,
                                                   float* __restrict__ sattn,
                                                   float* __restrict__ sums) {
    const int b = blockIdx.x;
    const int chunk = blockIdx.y;
    __shared__ float qs[NSL][FD];
    __shared__ float colsum[NSL];
    const int tid = threadIdx.x;
    for (int i = tid; i < NSL * FD; i += 256) qs[i / FD][i % FD] = Qs[(long)b * NSL * FD + i];
    if (tid < NSL) colsum[tid] = 0.0f;
    __syncthreads();
    const int wv = tid >> 6, lane = tid & 63;
    float wsum[NSL] = {};
#pragma unroll
    for (int rr = 0; rr < 4; rr++) {
        const int r = chunk * 16 + wv * 4 + rr;
        const float* kr = Kin + ((long)b * NN + r) * FD;
        float acc[NSL] = {};
#pragma unroll
        for (int i = 0; i < 5; i++) {
            const int t = lane + (i << 6);
            const float kv = kr[t];
#pragma unroll
            for (int s = 0; s < NSL; s++) acc[s] = fmaf(kv, qs[s][t], acc[s]);
        }
#pragma unroll
        for (int s = 0; s < NSL; s++)
#pragma unroll
            for (int o = 32; o; o >>= 1) acc[s] += __shfl_down(acc[s], o);
        if (lane == 0) {
            const float scale = 0.055901699437494740f;  // 1/sqrt(320)
            float mx = -1e30f;
#pragma unroll
            for (int s = 0; s < NSL; s++) { acc[s] *= scale; mx = fmaxf(mx, acc[s]); }
            float e[NSL], sum = 0.0f;
#pragma unroll
            for (int s = 0; s < NSL; s++) { e[s] = expf(acc[s] - mx); sum += e[s]; }
            const float rs = 1.0f / sum;
            float* outp = sattn + ((long)b * NN + r) * NSL;
#pragma unroll
            for (int s = 0; s < NSL; s++) {
                const float p = e[s] * rs;
                outp[s] = p;
                wsum[s] += p;
            }
        }
    }
    if (lane == 0) {
#pragma unroll
        for (int s = 0; s < NSL; s++) atomicAdd(&colsum[s], wsum[s]);
    }
    __syncthreads();
    if (tid < NSL) atomicAdd(&sums[b * NSL + tid], colsum[tid]);
}

// ---------------- slot updates (high occupancy) ----------------
// grid (BB, 4): each block accumulates 64 n-rows, atomicAdd into zeroed Upd.
// an[n][s] = (sattn + 1e-8) / (Sums[b][s] + 256e-8)
__global__ __launch_bounds__(256) void slot_updates(const float* __restrict__ sattn,
                                                    const float* __restrict__ sums,
                                                    const float* __restrict__ Vin,
                                                    float* __restrict__ Upd) {
    const int b = blockIdx.x;
    const int chunk = blockIdx.y;
    const int t = threadIdx.x;
    __shared__ float an[64][NSL];
    __shared__ float inv_s[NSL];
    if (t < NSL) inv_s[t] = 1.0f / (sums[b * NSL + t] + (float)NN * 1e-8f);
    __syncthreads();
    for (int i = t; i < 64 * NSL; i += 256) {
        const int s = i & 7;
        const int n = i >> 3;
        an[n][s] = (sattn[((long)b * NN + chunk * 64 + n) * NSL + s] + 1e-8f) * inv_s[s];
    }
    __syncthreads();
    float acc[NSL][2] = {};
    const float* vb = Vin + ((long)b * NN + chunk * 64) * FD;
    for (int n = 0; n < 64; n++) {
        const float v1 = vb[(long)n * FD + t];
        const float v2 = (t < 64) ? vb[(long)n * FD + 256 + t] : 0.0f;
#pragma unroll
        for (int s = 0; s < NSL; s++) {
            const float a = an[n][s];
            acc[s][0] = fmaf(a, v1, acc[s][0]);
            acc[s][1] = fmaf(a, v2, acc[s][1]);
        }
    }
    float* ub = Upd + (long)b * NSL * FD;
#pragma unroll
    for (int s = 0; s < NSL; s++) {
        atomicAdd(&ub[s * FD + t], acc[s][0]);
        if (t < 64) atomicAdd(&ub[s * FD + 256 + t], acc[s][1]);
    }
}

// ---------------- GRU elementwise combine ----------------
__global__ __launch_bounds__(256) void gru_elem(const float* __restrict__ GI,
                                                const float* __restrict__ GH,
                                                float* __restrict__ slots) {
    int idx = blockIdx.x * 256 + threadIdx.x;
    if (idx >= BB * NSL * FD) return;
    int r = idx / FD, f = idx % FD;
    const float* gi = GI + (long)r * 3 * FD;
    const float* gh = GH + (long)r * 3 * FD;
    float rr = sigm(gi[f] + gh[f]);
    float z = sigm(gi[FD + f] + gh[FD + f]);
    float nn = tanhf(gi[2 * FD + f] + rr * gh[2 * FD + f]);
    float h = slots[idx];
    slots[idx] = (1.0f - z) * nn + z * h;
}

// ---------------- output packing ----------------
__global__ __launch_bounds__(256) void write_out(const float* __restrict__ slots,
                                                 const float* __restrict__ sattn,
                                                 float* __restrict__ out) {
    int idx = blockIdx.x * 256 + threadIdx.x;
    const int SLOT_SZ = BB * NSL * FD;      // 163840
    const int MASK_SZ = BB * NSL * NN;      // 131072
    if (idx < SLOT_SZ) {
        out[idx] = slots[idx];
    } else if (idx < SLOT_SZ + MASK_SZ) {
        int i = idx - SLOT_SZ;
        int b = i >> 11;            // / (NSL*NN)
        int s = (i >> 8) & 7;
        int n = i & 255;
        out[idx] = sattn[((long)b * NN + n) * NSL + s];
    }
}

// ---------------- host launcher ----------------
extern "C" void kernel_launch(void* const* d_in, const int* in_sizes, int n_in,
                              void* d_out, int out_size, void* d_ws, size_t ws_size,
                              hipStream_t stream) {
    const float* state    = (const float*)d_in[0];
    const float* conv_w   = (const float*)d_in[1];
    const float* conv_b   = (const float*)d_in[2];
    const float* mlp_ln_g = (const float*)d_in[3];
    const float* mlp_ln_b = (const float*)d_in[4];
    const float* mlp_w1   = (const float*)d_in[5];
    const float* mlp_b1   = (const float*)d_in[6];
    const float* mlp_w2   = (const float*)d_in[7];
    const float* mlp_b2   = (const float*)d_in[8];
    const float* qkv_w    = (const float*)d_in[9];
    const float* qkv_b    = (const float*)d_in[10];
    const float* proj_w   = (const float*)d_in[11];
    const float* proj_b   = (const float*)d_in[12];
    const float* ni_g     = (const float*)d_in[13];
    const float* ni_b     = (const float*)d_in[14];
    const float* ns_g     = (const float*)d_in[15];
    const float* ns_b     = (const float*)d_in[16];
    const float* nm_g     = (const float*)d_in[17];
    const float* nm_b     = (const float*)d_in[18];
    const float* q_w      = (const float*)d_in[19];
    const float* k_w      = (const float*)d_in[20];
    const float* v_w      = (const float*)d_in[21];
    const float* gru_wih  = (const float*)d_in[22];
    const float* gru_whh  = (const float*)d_in[23];
    const float* gru_bih  = (const float*)d_in[24];
    const float* gru_bhh  = (const float*)d_in[25];
    const float* smlp_w1  = (const float*)d_in[26];
    const float* smlp_b1  = (const float*)d_in[27];
    const float* smlp_w2  = (const float*)d_in[28];
    const float* smlp_b2  = (const float*)d_in[29];

    float* ws = (float*)d_ws;
    const int M = BB * NN;  // 16384

    // workspace layout (floats), with lifetime-based reuse
    float* X0   = ws + 0L;            // 12.6M -> later QKV -> later S (16.78M region)
    float* QKV  = X0;
    float* S    = X0;
    float* X1   = ws + 16777216L;     // 4.19M -> later AO
    float* AO   = X1;
    float* XLN  = ws + 20971520L;     // 4.19M -> later Vt
    float* Vt   = XLN;
    float* Hbuf = ws + 25165824L;     // 8.39M -> later Qr+Kr
    float* Qr   = Hbuf;
    float* Kr   = Hbuf + 4194304L;
    float* X2   = ws + 33554432L;     // live until proj residual -> later Xn
    float* Xn   = X2;
    float* X3   = ws + 37748736L;
    float* Kin  = ws + 41943040L;     // 5.24M
    float* Vin  = ws + 47185920L;     // 5.24M
    float* Slots= ws + 52428800L;     // 163840
    float* SLn  = ws + 52592640L;     // 163840
    float* Qs   = ws + 52756480L;     // 163840
    float* Satt = ws + 52920320L;     // 131072
    float* Sums = ws + 53051392L;     // 512
    float* Upd  = ws + 53051904L;     // 163840
    float* GI   = ws + 53215744L;     // 491520
    float* GH   = ws + 53707264L;     // 491520
    float* Mh   = ws + 54198784L;     // 327680

    float* out = (float*)d_out;

    auto gemm = [&](const float* A, const float* W, const float* bias, const float* res,
                    float* C, int Mm, int Nn, int Kk, int batch,
                    long sA, long sW, long sC1, long sC2, int cdiv, int ldc,
                    float scale, int act) {
        dim3 grid(Nn / 64, Mm / 64, batch);
        if (act)
            gemm_nt<1><<<grid, 256, 0, stream>>>(A, W, bias, res, C, Mm, Nn, Kk,
                                                 sA, sW, sC1, sC2, cdiv, ldc, scale);
        else
            gemm_nt<0><<<grid, 256, 0, stream>>>(A, W, bias, res, C, Mm, Nn, Kk,
                                                 sA, sW, sC1, sC2, cdiv, ldc, scale);
    };

    // 1. sobel + onehot + im2col
    sobel_im2col<<<dim3((BB * HH * WW) / 256), 256, 0, stream>>>(state, X0);
    // 2. patch conv as GEMM
    gemm(X0, conv_w, conv_b, nullptr, X1, M, EE, KIM, 1, 0, 0, 0, 0, 1, EE, 1.0f, 0);
    // 3. LN + MLP
    ln_rows<<<dim3(M * 64 / 256), 256, 0, stream>>>(X1, XLN, mlp_ln_g, mlp_ln_b, M, EE);
    gemm(XLN, mlp_w1, mlp_b1, nullptr, Hbuf, M, 2 * EE, EE, 1, 0, 0, 0, 0, 1, 2 * EE, 1.0f, 1);
    gemm(Hbuf, mlp_w2, mlp_b2, nullptr, X2, M, EE, 2 * EE, 1, 0, 0, 0, 0, 1, EE, 1.0f, 0);
    // 4. QKV + RoPE
    gemm(X2, qkv_w, qkv_b, nullptr, QKV, M, 3 * EE, EE, 1, 0, 0, 0, 0, 1, 3 * EE, 1.0f, 0);
    rope_split<<<dim3((BB * NN * NHEAD * HD) / 256), 256, 0, stream>>>(QKV, Qr, Kr, Vt);
    // 5. attention: S = Q K^T * 0.125 ; softmax ; AO = P V
    gemm(Qr, Kr, nullptr, nullptr, S, NN, NN, HD, BB * NHEAD,
         (long)NN * HD, (long)NN * HD, (long)NN * NN, 0, 1, NN, 0.125f, 0);
    softmax256<<<dim3(BB * NHEAD * NN * 64 / 256), 256, 0, stream>>>(S, BB * NHEAD * NN);
    gemm(S, Vt, nullptr, nullptr, AO, NN, HD, NN, BB * NHEAD,
         (long)NN * NN, (long)NN * HD, (long)NN * EE, HD, NHEAD, EE, 1.0f, 0);
    // 6. proj + residual
    gemm(AO, proj_w, proj_b, X2, X3, M, EE, EE, 1, 0, 0, 0, 0, 1, EE, 1.0f, 0);
    // 7. LN ni, k_in, v_in
    ln_rows<<<dim3(M * 64 / 256), 256, 0, stream>>>(X3, Xn, ni_g, ni_b, M, EE);
    gemm(Xn, k_w, nullptr, nullptr, Kin, M, FD, EE, 1, 0, 0, 0, 0, 1, FD, 1.0f, 0);
    gemm(Xn, v_w, nullptr, nullptr, Vin, M, FD, EE, 1, 0, 0, 0, 0, 1, FD, 1.0f, 0);
    // 8. slot attention loop
    hipMemsetAsync(Slots, 0, (size_t)BB * NSL * FD * sizeof(float), stream);
    const int SR = BB * NSL;  // 512 slot rows
    for (int it = 0; it < 3; it++) {
        ln_rows<<<dim3(SR * 64 / 256), 256, 0, stream>>>(Slots, SLn, ns_g, ns_b, SR, FD);
        gemm(SLn, q_w, nullptr, nullptr, Qs, SR, FD, FD, 1, 0, 0, 0, 0, 1, FD, 1.0f, 0);
        hipMemsetAsync(Sums, 0, (size_t)BB * NSL * sizeof(float), stream);
        slot_logits<<<dim3(BB, 16), 256, 0, stream>>>(Kin, Qs, Satt, Sums);
        hipMemsetAsync(Upd, 0, (size_t)BB * NSL * FD * sizeof(float), stream);
        slot_updates<<<dim3(BB, 4), 256, 0, stream>>>(Satt, Sums, Vin, Upd);
        gemm(Upd, gru_wih, gru_bih, nullptr, GI, SR, 3 * FD, FD, 1, 0, 0, 0, 0, 1, 3 * FD, 1.0f, 0);
        gemm(Slots, gru_whh, gru_bhh, nullptr, GH, SR, 3 * FD, FD, 1, 0, 0, 0, 0, 1, 3 * FD, 1.0f, 0);
        gru_elem<<<dim3((SR * FD) / 256), 256, 0, stream>>>(GI, GH, Slots);
        ln_rows<<<dim3(SR * 64 / 256), 256, 0, stream>>>(Slots, SLn, nm_g, nm_b, SR, FD);
        gemm(SLn, smlp_w1, smlp_b1, nullptr, Mh, SR, 2 * FD, FD, 1, 0, 0, 0, 0, 1, 2 * FD, 1.0f, 1);
        gemm(Mh, smlp_w2, smlp_b2, Slots, Slots, SR, FD, 2 * FD, 1, 0, 0, 0, 0, 1, FD, 1.0f, 0);
    }
    // 9. outputs
    write_out<<<dim3((BB * NSL * FD + BB * NSL * NN + 255) / 256), 256, 0, stream>>>(Slots, Satt, out);
}

// Round 3
// 952.849 us; speedup vs baseline: 1.8716x; 1.3741x over previous
//
#include <hip/hip_runtime.h>
#include <math.h>

// ---------------- problem constants ----------------
#define BB   64
#define HH   128
#define WW   128
#define GG   16
#define NN   256     // G*G tokens
#define EE   256
#define FD   320
#define NSL  8       // slots
#define NHEAD 4
#define HD   64
#define KIM  768     // 12*8*8 im2col K

using short8 = __attribute__((ext_vector_type(8))) short;
using f32x4  = __attribute__((ext_vector_type(4))) float;

__device__ __forceinline__ float sigm(float x) { return 1.0f / (1.0f + expf(-x)); }
__device__ __forceinline__ float gelu_exact(float x) {
    return 0.5f * x * (1.0f + erff(x * 0.70710678118654752f));
}
// round-to-nearest-even f32 -> bf16
__device__ __forceinline__ unsigned short f2b(float x) {
    unsigned u = __float_as_uint(x);
    u += 0x7fffu + ((u >> 16) & 1u);
    return (unsigned short)(u >> 16);
}
__device__ __forceinline__ void gload_lds16(const void* g, void* lds) {
    __builtin_amdgcn_global_load_lds(
        (const __attribute__((address_space(1))) unsigned int*)g,
        (__attribute__((address_space(3))) unsigned int*)lds, 16, 0, 0);
}
__device__ __forceinline__ void store_el(float* p, float v) { *p = v; }
__device__ __forceinline__ void store_el(unsigned short* p, float v) { *p = f2b(v); }

// ---------------- fp32 -> bf16 convert ----------------
__global__ __launch_bounds__(256) void cvt_bf16(const float* __restrict__ in,
                                                unsigned short* __restrict__ out, int n) {
    int i = blockIdx.x * 256 + threadIdx.x;
    if (i < n) out[i] = f2b(in[i]);
}

// ---------------- Sobel + one-hot + im2col (bf16 out, exact) ----------------
__global__ __launch_bounds__(256) void sobel_im2col(const float* __restrict__ state,
                                                    unsigned short* __restrict__ X0) {
    int idx = blockIdx.x * 256 + threadIdx.x;
    if (idx >= BB * HH * WW) return;
    int w = idx % WW;
    int h = (idx / WW) % HH;
    int b = idx / (HH * WW);
    const float* st = state + (long)b * HH * WW;
    auto at = [&](int y, int x) {
        y = min(max(y, 0), HH - 1);
        x = min(max(x, 0), WW - 1);
        return st[y * WW + x];
    };
    float v00 = at(h-1, w-1), v01 = at(h-1, w), v02 = at(h-1, w+1);
    float v10 = at(h,   w-1),                  v12 = at(h,   w+1);
    float v20 = at(h+1, w-1), v21 = at(h+1, w), v22 = at(h+1, w+1);
    float sx = (v02 - v00) + 2.0f * (v12 - v10) + (v22 - v20);
    float sy = (v20 - v00) + 2.0f * (v21 - v01) + (v22 - v02);
    int id = (int)st[h * WW + w];
    int gy = h >> 3, i = h & 7, gx = w >> 3, j = w & 7;
    long row = (long)b * NN + gy * GG + gx;
    unsigned short* xr = X0 + row * KIM + i * 8 + j;
#pragma unroll
    for (int c = 0; c < 10; c++) xr[c * 64] = (id == c) ? 0x3F80u : 0u;
    xr[10 * 64] = f2b(sx);
    xr[11 * 64] = f2b(sy);
}

// ---------------- bf16 MFMA NT GEMM ----------------
// C[m][n] = act(scale * sum_k A[m][k]*W[n][k] + bias[n]) (+res) -> C (f32) and/or Cb (bf16)
// A: [M][K] bf16 row-major, W: [N][K] bf16 row-major. K%32==0, M%BM==0, N%BN==0.
// BM*BN must equal 16384 (4 waves of 64x64).
template <int BM, int BN, int ACT>
__global__ __launch_bounds__(256) void gemm_bf16(
    const unsigned short* __restrict__ A, const unsigned short* __restrict__ W,
    const float* __restrict__ bias, const float* __restrict__ res,
    float* __restrict__ C, unsigned short* __restrict__ Cb,
    int K, long sA, long sW, long sC1, long sC2, int cdiv, int ldc, float scale)
{
    constexpr int WN = BN / 64;      // waves along N
    __shared__ __align__(16) unsigned short As[BM * 32];
    __shared__ __align__(16) unsigned short Bs[BN * 32];
    const int tid = threadIdx.x;
    const int w = tid >> 6, l = tid & 63;
    const int wm = w / WN, wn = w % WN;
    const int bz = blockIdx.z;
    const unsigned short* Ab = A + (long)bz * sA + (long)(blockIdx.y * BM) * K;
    const unsigned short* Wb = W + (long)bz * sW + (long)(blockIdx.x * BN) * K;
    const long offC = (long)(bz / cdiv) * sC1 + (long)(bz % cdiv) * sC2;

    // staging: lane l covers (row = chunk*16 + (l>>2), 16B slot = l&3), source k8 pre-swizzled
    const int rA  = l >> 2;
    const int swz = ((l & 3) ^ ((l >> 3) & 3)) * 8;   // k-element offset (bf16 units)

    f32x4 acc[4][4] = {};

    for (int k0 = 0; k0 < K; k0 += 32) {
#pragma unroll
        for (int c = 0; c < BM / 64; c++) {
            const int chunk = w * (BM / 64) + c;
            gload_lds16(Ab + (long)(chunk * 16 + rA) * K + k0 + swz, (char*)As + chunk * 1024);
        }
#pragma unroll
        for (int c = 0; c < BN / 64; c++) {
            const int chunk = w * (BN / 64) + c;
            gload_lds16(Wb + (long)(chunk * 16 + rA) * K + k0 + swz, (char*)Bs + chunk * 1024);
        }
        __syncthreads();
        short8 af[4], bfr[4];
#pragma unroll
        for (int m = 0; m < 4; m++) {
            const int row = wm * 64 + m * 16 + (l & 15);
            const int byte = row * 64 + (((l >> 4) ^ ((row >> 1) & 3)) << 4);
            af[m] = *(const short8*)((const char*)As + byte);
        }
#pragma unroll
        for (int n = 0; n < 4; n++) {
            const int row = wn * 64 + n * 16 + (l & 15);
            const int byte = row * 64 + (((l >> 4) ^ ((row >> 1) & 3)) << 4);
            bfr[n] = *(const short8*)((const char*)Bs + byte);
        }
#pragma unroll
        for (int m = 0; m < 4; m++)
#pragma unroll
            for (int n = 0; n < 4; n++)
                acc[m][n] = __builtin_amdgcn_mfma_f32_16x16x32_bf16(af[m], bfr[n], acc[m][n], 0, 0, 0);
        __syncthreads();
    }

    const int crow0 = blockIdx.y * BM + wm * 64;
    const int ccol0 = blockIdx.x * BN + wn * 64;
#pragma unroll
    for (int m = 0; m < 4; m++) {
#pragma unroll
        for (int n = 0; n < 4; n++) {
            const int row = crow0 + m * 16 + ((l >> 4) << 2);
            const int col = ccol0 + n * 16 + (l & 15);
#pragma unroll
            for (int r = 0; r < 4; r++) {
                float v = acc[m][n][r] * scale;
                if (bias) v += bias[col];
                if (ACT == 1) v = gelu_exact(v);
                const long idx = offC + (long)(row + r) * ldc + col;
                if (res) v += res[idx];
                if (C)  C[idx] = v;
                if (Cb) Cb[idx] = f2b(v);
            }
        }
    }
}

// ---------------- fp32 tile GEMM (slot loop, small M) ----------------
template <int ACT>
__global__ __launch_bounds__(256) void gemm_nt(
    const float* __restrict__ A, const float* __restrict__ W,
    const float* __restrict__ bias, const float* __restrict__ res,
    float* __restrict__ C, int M, int N, int K,
    long sA, long sW, long sC1, long sC2, int cdiv, int ldc, float scale)
{
    const int bz = blockIdx.z;
    const float* Ab = A + (long)bz * sA;
    const float* Wb = W + (long)bz * sW;
    const long offC = (long)(bz / cdiv) * sC1 + (long)(bz % cdiv) * sC2;
    float* Cb = C + offC;
    const float* Rb = res ? res + offC : nullptr;

    __shared__ float As[16][68];
    __shared__ float Ws[16][68];

    const int tid = threadIdx.x;
    const int tx = tid & 15;
    const int ty = tid >> 4;
    const int row0 = blockIdx.y << 6;
    const int col0 = blockIdx.x << 6;

    float acc[4][4] = {};

    for (int k0 = 0; k0 < K; k0 += 16) {
#pragma unroll
        for (int i = 0; i < 4; i++) {
            const int idx = tid + (i << 8);
            const int m = idx >> 4;
            const int kk = idx & 15;
            As[kk][m] = Ab[(long)(row0 + m) * K + (k0 + kk)];
            Ws[kk][m] = Wb[(long)(col0 + m) * K + (k0 + kk)];
        }
        __syncthreads();
#pragma unroll
        for (int kk = 0; kk < 16; kk++) {
            const float4 a4 = *(const float4*)&As[kk][ty << 2];
            const float4 b4 = *(const float4*)&Ws[kk][tx << 2];
            const float a[4] = {a4.x, a4.y, a4.z, a4.w};
            const float b[4] = {b4.x, b4.y, b4.z, b4.w};
#pragma unroll
            for (int i = 0; i < 4; i++)
#pragma unroll
                for (int j = 0; j < 4; j++)
                    acc[i][j] = fmaf(a[i], b[j], acc[i][j]);
        }
        __syncthreads();
    }

    const int crow = row0 + (ty << 2);
    const int ccol = col0 + (tx << 2);
#pragma unroll
    for (int i = 0; i < 4; i++) {
#pragma unroll
        for (int j = 0; j < 4; j++) {
            float v = acc[i][j] * scale;
            if (bias) v += bias[ccol + j];
            if (ACT == 1) v = gelu_exact(v);
            if (Rb) v += Rb[(long)(crow + i) * ldc + (ccol + j)];
            Cb[(long)(crow + i) * ldc + (ccol + j)] = v;
        }
    }
}

// ---------------- LayerNorm (wave per row), templated output ----------------
template <typename OT>
__global__ __launch_bounds__(256) void ln_rows(const float* __restrict__ X,
                                               OT* __restrict__ Y,
                                               const float* __restrict__ g,
                                               const float* __restrict__ b,
                                               int rows, int D) {
    int gtid = blockIdx.x * 256 + threadIdx.x;
    int row = gtid >> 6;
    int lane = gtid & 63;
    if (row >= rows) return;
    const float* x = X + (long)row * D;
    const int nv = D >> 6;
    float v[5];
    float s = 0.0f;
#pragma unroll 5
    for (int i = 0; i < nv; i++) { v[i] = x[lane + (i << 6)]; s += v[i]; }
#pragma unroll
    for (int o = 32; o; o >>= 1) s += __shfl_down(s, o);
    s = __shfl(s, 0);
    float mean = s / (float)D;
    float s2 = 0.0f;
#pragma unroll 5
    for (int i = 0; i < nv; i++) { float d = v[i] - mean; s2 += d * d; }
#pragma unroll
    for (int o = 32; o; o >>= 1) s2 += __shfl_down(s2, o);
    s2 = __shfl(s2, 0);
    float inv = rsqrtf(s2 / (float)D + 1e-5f);
    OT* y = Y + (long)row * D;
#pragma unroll 5
    for (int i = 0; i < nv; i++) {
        int d = lane + (i << 6);
        store_el(&y[d], (v[i] - mean) * inv * g[d] + b[d]);
    }
}

// ---------------- RoPE + head split (bf16 out) ----------------
__global__ __launch_bounds__(256) void rope_split(const float* __restrict__ QKV,
                                                  unsigned short* __restrict__ Qr,
                                                  unsigned short* __restrict__ Kr,
                                                  unsigned short* __restrict__ Vt) {
    int idx = blockIdx.x * 256 + threadIdx.x;
    if (idx >= BB * NN * NHEAD * HD) return;
    int d = idx & 63;
    int h = (idx >> 6) & 3;
    int n = (idx >> 8) & 255;
    int b = idx >> 16;
    long row = (long)b * NN + n;
    const float* base = QKV + row * 768 + h * 64;

    int pos = (d < 32) ? (n >> 4) : (n & 15);
    int j = d & 31;
    float ang;
    if (j < 16) ang = sinf((float)pos * powf(10000.0f, -(float)j / 16.0f));
    else        ang = cosf((float)pos * powf(10000.0f, -(float)(j - 16) / 16.0f));
    float cv = cosf(ang), sv = sinf(ang);

    float xq = base[d];
    float rq = (d < 32) ? -base[2 * d + 1] : base[2 * (d - 32)];
    float xk = base[256 + d];
    float rk = (d < 32) ? -base[256 + 2 * d + 1] : base[256 + 2 * (d - 32)];

    long bh = (long)b * NHEAD + h;
    Qr[bh * (NN * HD) + (long)n * HD + d] = f2b(xq * cv + rq * sv);
    Kr[bh * (NN * HD) + (long)n * HD + d] = f2b(xk * cv + rk * sv);
    Vt[bh * (NN * HD) + (long)d * NN + n] = f2b(base[512 + d]);
}

// ---------------- attention softmax: fp32 S -> bf16 P ----------------
__global__ __launch_bounds__(256) void softmax_p(const float* __restrict__ S,
                                                 unsigned short* __restrict__ P, int rows) {
    int gtid = blockIdx.x * 256 + threadIdx.x;
    int row = gtid >> 6;
    int lane = gtid & 63;
    if (row >= rows) return;
    const float* r = S + (long)row * 256;
    float v[4];
    float m = -1e30f;
#pragma unroll
    for (int i = 0; i < 4; i++) { v[i] = r[lane + (i << 6)]; m = fmaxf(m, v[i]); }
#pragma unroll
    for (int o = 32; o; o >>= 1) m = fmaxf(m, __shfl_down(m, o));
    m = __shfl(m, 0);
    float s = 0.0f;
#pragma unroll
    for (int i = 0; i < 4; i++) { v[i] = expf(v[i] - m); s += v[i]; }
#pragma unroll
    for (int o = 32; o; o >>= 1) s += __shfl_down(s, o);
    s = __shfl(s, 0);
    float inv = 1.0f / s;
    unsigned short* p = P + (long)row * 256;
#pragma unroll
    for (int i = 0; i < 4; i++) p[lane + (i << 6)] = f2b(v[i] * inv);
}

// ---------------- slot logits + softmax over slots ----------------
__global__ __launch_bounds__(256) void slot_logits(const float* __restrict__ Kin,
                                                   const float* __restrict__ Qs,
                                                   float* __restrict__ sattn,
                                                   float* __restrict__ sums) {
    const int b = blockIdx.x;
    const int chunk = blockIdx.y;
    __shared__ float qs[NSL][FD];
    __shared__ float colsum[NSL];
    const int tid = threadIdx.x;
    for (int i = tid; i < NSL * FD; i += 256) qs[i / FD][i % FD] = Qs[(long)b * NSL * FD + i];
    if (tid < NSL) colsum[tid] = 0.0f;
    __syncthreads();
    const int wv = tid >> 6, lane = tid & 63;
    float wsum[NSL] = {};
#pragma unroll
    for (int rr = 0; rr < 4; rr++) {
        const int r = chunk * 16 + wv * 4 + rr;
        const float* kr = Kin + ((long)b * NN + r) * FD;
        float acc[NSL] = {};
#pragma unroll
        for (int i = 0; i < 5; i++) {
            const int t = lane + (i << 6);
            const float kv = kr[t];
#pragma unroll
            for (int s = 0; s < NSL; s++) acc[s] = fmaf(kv, qs[s][t], acc[s]);
        }
#pragma unroll
        for (int s = 0; s < NSL; s++)
#pragma unroll
            for (int o = 32; o; o >>= 1) acc[s] += __shfl_down(acc[s], o);
        if (lane == 0) {
            const float scale = 0.055901699437494740f;  // 1/sqrt(320)
            float mx = -1e30f;
#pragma unroll
            for (int s = 0; s < NSL; s++) { acc[s] *= scale; mx = fmaxf(mx, acc[s]); }
            float e[NSL], sum = 0.0f;
#pragma unroll
            for (int s = 0; s < NSL; s++) { e[s] = expf(acc[s] - mx); sum += e[s]; }
            const float rs = 1.0f / sum;
            float* outp = sattn + ((long)b * NN + r) * NSL;
#pragma unroll
            for (int s = 0; s < NSL; s++) {
                const float p = e[s] * rs;
                outp[s] = p;
                wsum[s] += p;
            }
        }
    }
    if (lane == 0) {
#pragma unroll
        for (int s = 0; s < NSL; s++) atomicAdd(&colsum[s], wsum[s]);
    }
    __syncthreads();
    if (tid < NSL) atomicAdd(&sums[b * NSL + tid], colsum[tid]);
}

// ---------------- slot updates ----------------
__global__ __launch_bounds__(256) void slot_updates(const float* __restrict__ sattn,
                                                    const float* __restrict__ sums,
                                                    const float* __restrict__ Vin,
                                                    float* __restrict__ Upd) {
    const int b = blockIdx.x;
    const int chunk = blockIdx.y;
    const int t = threadIdx.x;
    __shared__ float an[64][NSL];
    __shared__ float inv_s[NSL];
    if (t < NSL) inv_s[t] = 1.0f / (sums[b * NSL + t] + (float)NN * 1e-8f);
    __syncthreads();
    for (int i = t; i < 64 * NSL; i += 256) {
        const int s = i & 7;
        const int n = i >> 3;
        an[n][s] = (sattn[((long)b * NN + chunk * 64 + n) * NSL + s] + 1e-8f) * inv_s[s];
    }
    __syncthreads();
    float acc[NSL][2] = {};
    const float* vb = Vin + ((long)b * NN + chunk * 64) * FD;
    for (int n = 0; n < 64; n++) {
        const float v1 = vb[(long)n * FD + t];
        const float v2 = (t < 64) ? vb[(long)n * FD + 256 + t] : 0.0f;
#pragma unroll
        for (int s = 0; s < NSL; s++) {
            const float a = an[n][s];
            acc[s][0] = fmaf(a, v1, acc[s][0]);
            acc[s][1] = fmaf(a, v2, acc[s][1]);
        }
    }
    float* ub = Upd + (long)b * NSL * FD;
#pragma unroll
    for (int s = 0; s < NSL; s++) {
        atomicAdd(&ub[s * FD + t], acc[s][0]);
        if (t < 64) atomicAdd(&ub[s * FD + 256 + t], acc[s][1]);
    }
}

// ---------------- GRU elementwise ----------------
__global__ __launch_bounds__(256) void gru_elem(const float* __restrict__ GI,
                                                const float* __restrict__ GH,
                                                float* __restrict__ slots) {
    int idx = blockIdx.x * 256 + threadIdx.x;
    if (idx >= BB * NSL * FD) return;
    int r = idx / FD, f = idx % FD;
    const float* gi = GI + (long)r * 3 * FD;
    const float* gh = GH + (long)r * 3 * FD;
    float rr = sigm(gi[f] + gh[f]);
    float z = sigm(gi[FD + f] + gh[FD + f]);
    float nn = tanhf(gi[2 * FD + f] + rr * gh[2 * FD + f]);
    float h = slots[idx];
    slots[idx] = (1.0f - z) * nn + z * h;
}

// ---------------- output packing ----------------
__global__ __launch_bounds__(256) void write_out(const float* __restrict__ slots,
                                                 const float* __restrict__ sattn,
                                                 float* __restrict__ out) {
    int idx = blockIdx.x * 256 + threadIdx.x;
    const int SLOT_SZ = BB * NSL * FD;
    const int MASK_SZ = BB * NSL * NN;
    if (idx < SLOT_SZ) {
        out[idx] = slots[idx];
    } else if (idx < SLOT_SZ + MASK_SZ) {
        int i = idx - SLOT_SZ;
        int b = i >> 11;
        int s = (i >> 8) & 7;
        int n = i & 255;
        out[idx] = sattn[((long)b * NN + n) * NSL + s];
    }
}

// ---------------- host launcher ----------------
extern "C" void kernel_launch(void* const* d_in, const int* in_sizes, int n_in,
                              void* d_out, int out_size, void* d_ws, size_t ws_size,
                              hipStream_t stream) {
    const float* state    = (const float*)d_in[0];
    const float* conv_w   = (const float*)d_in[1];
    const float* conv_b   = (const float*)d_in[2];
    const float* mlp_ln_g = (const float*)d_in[3];
    const float* mlp_ln_b = (const float*)d_in[4];
    const float* mlp_w1   = (const float*)d_in[5];
    const float* mlp_b1   = (const float*)d_in[6];
    const float* mlp_w2   = (const float*)d_in[7];
    const float* mlp_b2   = (const float*)d_in[8];
    const float* qkv_w    = (const float*)d_in[9];
    const float* qkv_b    = (const float*)d_in[10];
    const float* proj_w   = (const float*)d_in[11];
    const float* proj_b   = (const float*)d_in[12];
    const float* ni_g     = (const float*)d_in[13];
    const float* ni_b     = (const float*)d_in[14];
    const float* ns_g     = (const float*)d_in[15];
    const float* ns_b     = (const float*)d_in[16];
    const float* nm_g     = (const float*)d_in[17];
    const float* nm_b     = (const float*)d_in[18];
    const float* q_w      = (const float*)d_in[19];
    const float* k_w      = (const float*)d_in[20];
    const float* v_w      = (const float*)d_in[21];
    const float* gru_wih  = (const float*)d_in[22];
    const float* gru_whh  = (const float*)d_in[23];
    const float* gru_bih  = (const float*)d_in[24];
    const float* gru_bhh  = (const float*)d_in[25];
    const float* smlp_w1  = (const float*)d_in[26];
    const float* smlp_b1  = (const float*)d_in[27];
    const float* smlp_w2  = (const float*)d_in[28];
    const float* smlp_b2  = (const float*)d_in[29];

    float* ws = (float*)d_ws;
    const int M = BB * NN;  // 16384
    typedef unsigned short u16;

    // ---- workspace layout (float units; bf16 buffers use 2 elems/float) ----
    // Region A [0, 6291456): X0b -> Qr/Kr/Vt
    u16*   X0b  = (u16*)(ws + 0L);
    u16*   Qr   = (u16*)(ws + 0L);
    u16*   Kr   = (u16*)(ws + 2097152L);
    u16*   Vt   = (u16*)(ws + 4194304L);
    // Region B [6291456, 23068672): X1/XLNb/Hbufb -> QKV -> S
    float* X1   = ws + 6291456L;
    u16*   XLNb = (u16*)(ws + 10485760L);
    u16*   Hbufb= (u16*)(ws + 12582912L);
    float* QKV  = ws + 6291456L;
    float* S    = ws + 6291456L;
    // Region C [23068672, 31457280): X2b -> P
    u16*   X2b  = (u16*)(ws + 23068672L);
    u16*   P    = (u16*)(ws + 23068672L);
    // Region D [31457280, 35651584): X2 -> Xnb
    float* X2   = ws + 31457280L;
    u16*   Xnb  = (u16*)(ws + 31457280L);
    // Region E [35651584, 39845888): X3 -> slot buffers
    float* X3   = ws + 35651584L;
    float* Slots= ws + 35651584L;
    float* SLn  = ws + 35815424L;
    float* Qs   = ws + 35979264L;
    float* Satt = ws + 36143104L;
    float* Sums = ws + 36274176L;
    float* Upd  = ws + 36274688L;
    float* GI   = ws + 36438528L;
    float* GH   = ws + 36930048L;
    float* Mh   = ws + 37421568L;
    // Region F/G: Kin, Vin
    float* Kin  = ws + 39845888L;
    float* Vin  = ws + 45088768L;
    // Region H: AOb + bf16 weights
    u16*   AOb    = (u16*)(ws + 50331648L);
    u16*   conv_wb= (u16*)(ws + 52428800L);
    u16*   mlp_w1b= (u16*)(ws + 52527104L);
    u16*   mlp_w2b= (u16*)(ws + 52592640L);
    u16*   qkv_wb = (u16*)(ws + 52658176L);
    u16*   proj_wb= (u16*)(ws + 52756480L);
    u16*   k_wb   = (u16*)(ws + 52789248L);
    u16*   v_wb   = (u16*)(ws + 52830208L);

    float* out = (float*)d_out;

    auto cvt = [&](const float* in, u16* o, int n) {
        cvt_bf16<<<dim3((n + 255) / 256), 256, 0, stream>>>(in, o, n);
    };
    auto gemmA = [&](const u16* A, const u16* Wt, const float* bias, const float* res,
                     float* C, u16* Cb, int Mm, int Nn, int Kk, int batch,
                     long sA, long sW, long sC1, long sC2, int cdiv, int ldc,
                     float scale, int act) {
        dim3 grid(Nn / 128, Mm / 128, batch);
        if (act) gemm_bf16<128, 128, 1><<<grid, 256, 0, stream>>>(A, Wt, bias, res, C, Cb, Kk, sA, sW, sC1, sC2, cdiv, ldc, scale);
        else     gemm_bf16<128, 128, 0><<<grid, 256, 0, stream>>>(A, Wt, bias, res, C, Cb, Kk, sA, sW, sC1, sC2, cdiv, ldc, scale);
    };
    auto gemmB = [&](const u16* A, const u16* Wt, const float* bias, const float* res,
                     float* C, u16* Cb, int Mm, int Nn, int Kk, int batch,
                     long sA, long sW, long sC1, long sC2, int cdiv, int ldc,
                     float scale) {
        dim3 grid(Nn / 64, Mm / 256, batch);
        gemm_bf16<256, 64, 0><<<grid, 256, 0, stream>>>(A, Wt, bias, res, C, Cb, Kk, sA, sW, sC1, sC2, cdiv, ldc, scale);
    };
    auto gemmF = [&](const float* A, const float* Wt, const float* bias, const float* res,
                     float* C, int Mm, int Nn, int Kk, float scale, int act) {
        dim3 grid(Nn / 64, Mm / 64, 1);
        if (act) gemm_nt<1><<<grid, 256, 0, stream>>>(A, Wt, bias, res, C, Mm, Nn, Kk, 0, 0, 0, 0, 1, Nn, scale);
        else     gemm_nt<0><<<grid, 256, 0, stream>>>(A, Wt, bias, res, C, Mm, Nn, Kk, 0, 0, 0, 0, 1, Nn, scale);
    };

    // 0. weight conversions (bf16)
    cvt(conv_w, conv_wb, EE * KIM);
    cvt(mlp_w1, mlp_w1b, 2 * EE * EE);
    cvt(mlp_w2, mlp_w2b, 2 * EE * EE);
    cvt(qkv_w, qkv_wb, 3 * EE * EE);
    cvt(proj_w, proj_wb, EE * EE);
    cvt(k_w, k_wb, FD * EE);
    cvt(v_w, v_wb, FD * EE);

    // 1. sobel + onehot + im2col (bf16)
    sobel_im2col<<<dim3((BB * HH * WW) / 256), 256, 0, stream>>>(state, X0b);
    // 2. patch conv as GEMM (bf16 MFMA) -> X1 fp32
    gemmA(X0b, conv_wb, conv_b, nullptr, X1, nullptr, M, EE, KIM, 1, 0, 0, 0, 0, 1, EE, 1.0f, 0);
    // 3. LN -> bf16, MLP
    ln_rows<u16><<<dim3(M * 64 / 256), 256, 0, stream>>>(X1, XLNb, mlp_ln_g, mlp_ln_b, M, EE);
    gemmA(XLNb, mlp_w1b, mlp_b1, nullptr, nullptr, Hbufb, M, 2 * EE, EE, 1, 0, 0, 0, 0, 1, 2 * EE, 1.0f, 1);
    gemmA(Hbufb, mlp_w2b, mlp_b2, nullptr, X2, X2b, M, EE, 2 * EE, 1, 0, 0, 0, 0, 1, EE, 1.0f, 0);
    // 4. QKV + RoPE
    gemmA(X2b, qkv_wb, qkv_b, nullptr, QKV, nullptr, M, 3 * EE, EE, 1, 0, 0, 0, 0, 1, 3 * EE, 1.0f, 0);
    rope_split<<<dim3((BB * NN * NHEAD * HD) / 256), 256, 0, stream>>>(QKV, Qr, Kr, Vt);
    // 5. attention
    gemmA(Qr, Kr, nullptr, nullptr, S, nullptr, NN, NN, HD, BB * NHEAD,
          (long)NN * HD, (long)NN * HD, (long)NN * NN, 0, 1, NN, 0.125f, 0);
    softmax_p<<<dim3(BB * NHEAD * NN * 64 / 256), 256, 0, stream>>>(S, P, BB * NHEAD * NN);
    gemmB(P, Vt, nullptr, nullptr, nullptr, AOb, NN, HD, NN, BB * NHEAD,
          (long)NN * NN, (long)NN * HD, (long)NN * EE, HD, NHEAD, EE, 1.0f);
    // 6. proj + residual -> X3 fp32
    gemmA(AOb, proj_wb, proj_b, X2, X3, nullptr, M, EE, EE, 1, 0, 0, 0, 0, 1, EE, 1.0f, 0);
    // 7. LN ni -> bf16, k_in / v_in (fp32 out)
    ln_rows<u16><<<dim3(M * 64 / 256), 256, 0, stream>>>(X3, Xnb, ni_g, ni_b, M, EE);
    gemmB(Xnb, k_wb, nullptr, nullptr, Kin, nullptr, M, FD, EE, 1, 0, 0, 0, 0, 1, FD, 1.0f);
    gemmB(Xnb, v_wb, nullptr, nullptr, Vin, nullptr, M, FD, EE, 1, 0, 0, 0, 0, 1, FD, 1.0f);
    // 8. slot attention loop (fp32)
    hipMemsetAsync(Slots, 0, (size_t)BB * NSL * FD * sizeof(float), stream);
    const int SR = BB * NSL;  // 512
    for (int it = 0; it < 3; it++) {
        ln_rows<float><<<dim3(SR * 64 / 256), 256, 0, stream>>>(Slots, SLn, ns_g, ns_b, SR, FD);
        gemmF(SLn, q_w, nullptr, nullptr, Qs, SR, FD, FD, 1.0f, 0);
        hipMemsetAsync(Sums, 0, (size_t)BB * NSL * sizeof(float), stream);
        slot_logits<<<dim3(BB, 16), 256, 0, stream>>>(Kin, Qs, Satt, Sums);
        hipMemsetAsync(Upd, 0, (size_t)BB * NSL * FD * sizeof(float), stream);
        slot_updates<<<dim3(BB, 4), 256, 0, stream>>>(Satt, Sums, Vin, Upd);
        gemmF(Upd, gru_wih, gru_bih, nullptr, GI, SR, 3 * FD, FD, 1.0f, 0);
        gemmF(Slots, gru_whh, gru_bhh, nullptr, GH, SR, 3 * FD, FD, 1.0f, 0);
        gru_elem<<<dim3((SR * FD) / 256), 256, 0, stream>>>(GI, GH, Slots);
        ln_rows<float><<<dim3(SR * 64 / 256), 256, 0, stream>>>(Slots, SLn, nm_g, nm_b, SR, FD);
        gemmF(SLn, smlp_w1, smlp_b1, nullptr, Mh, SR, 2 * FD, FD, 1.0f, 1);
        gemmF(Mh, smlp_w2, smlp_b2, Slots, Slots, SR, FD, 2 * FD, 1.0f, 0);
    }
    // 9. outputs
    write_out<<<dim3((BB * NSL * FD + BB * NSL * NN + 255) / 256), 256, 0, stream>>>(Slots, Satt, out);
}

// Round 4
// 886.514 us; speedup vs baseline: 2.0116x; 1.0748x over previous
//
#include <hip/hip_runtime.h>
#include <math.h>

// ---------------- problem constants ----------------
#define BB   64
#define HH   128
#define WW   128
#define GG   16
#define NN   256     // G*G tokens
#define EE   256
#define FD   320
#define NSL  8       // slots
#define NHEAD 4
#define HD   64
#define KIM  768     // 12*8*8 im2col K

using short8 = __attribute__((ext_vector_type(8))) short;
using f32x4  = __attribute__((ext_vector_type(4))) float;

__device__ __forceinline__ float sigm(float x) { return 1.0f / (1.0f + expf(-x)); }
__device__ __forceinline__ float gelu_exact(float x) {
    return 0.5f * x * (1.0f + erff(x * 0.70710678118654752f));
}
// round-to-nearest-even f32 -> bf16
__device__ __forceinline__ unsigned short f2b(float x) {
    unsigned u = __float_as_uint(x);
    u += 0x7fffu + ((u >> 16) & 1u);
    return (unsigned short)(u >> 16);
}
__device__ __forceinline__ float b2f(unsigned short u) {
    return __uint_as_float(((unsigned)u) << 16);
}
__device__ __forceinline__ void gload_lds16(const void* g, void* lds) {
    __builtin_amdgcn_global_load_lds(
        (const __attribute__((address_space(1))) unsigned int*)g,
        (__attribute__((address_space(3))) unsigned int*)lds, 16, 0, 0);
}
__device__ __forceinline__ void store_el(float* p, float v) { *p = v; }
__device__ __forceinline__ void store_el(unsigned short* p, float v) { *p = f2b(v); }

// ---------------- all weight conversions in one kernel ----------------
// dst is one contiguous bf16 region; segment boundaries are compile-time.
__global__ __launch_bounds__(256) void cvt_weights(
    const float* __restrict__ w0, const float* __restrict__ w1,
    const float* __restrict__ w2, const float* __restrict__ w3,
    const float* __restrict__ w4, const float* __restrict__ w5,
    const float* __restrict__ w6, unsigned short* __restrict__ dst) {
    int i = blockIdx.x * 256 + threadIdx.x;   // < 884736
    float v;
    if      (i < 196608) v = w0[i];
    else if (i < 327680) v = w1[i - 196608];
    else if (i < 458752) v = w2[i - 327680];
    else if (i < 655360) v = w3[i - 458752];
    else if (i < 720896) v = w4[i - 655360];
    else if (i < 802816) v = w5[i - 720896];
    else                 v = w6[i - 802816];
    dst[i] = f2b(v);
}

// ---------------- RoPE tables: cs/sn[n][d], n<256, d<64 ----------------
__global__ __launch_bounds__(256) void rope_tab(float* __restrict__ cs,
                                                float* __restrict__ sn) {
    int i = blockIdx.x * 256 + threadIdx.x;   // 16384
    int d = i & 63, n = i >> 6;
    int pos = (d < 32) ? (n >> 4) : (n & 15);
    int j = d & 31;
    float freq = powf(10000.0f, -(float)(j & 15) / 16.0f);
    float p = (float)pos * freq;
    float ang = (j < 16) ? sinf(p) : cosf(p);
    cs[i] = cosf(ang);
    sn[i] = sinf(ang);
}

// ---------------- Sobel + one-hot + im2col (bf16 out, exact) ----------------
__global__ __launch_bounds__(256) void sobel_im2col(const float* __restrict__ state,
                                                    unsigned short* __restrict__ X0) {
    int idx = blockIdx.x * 256 + threadIdx.x;
    if (idx >= BB * HH * WW) return;
    int w = idx % WW;
    int h = (idx / WW) % HH;
    int b = idx / (HH * WW);
    const float* st = state + (long)b * HH * WW;
    auto at = [&](int y, int x) {
        y = min(max(y, 0), HH - 1);
        x = min(max(x, 0), WW - 1);
        return st[y * WW + x];
    };
    float v00 = at(h-1, w-1), v01 = at(h-1, w), v02 = at(h-1, w+1);
    float v10 = at(h,   w-1),                  v12 = at(h,   w+1);
    float v20 = at(h+1, w-1), v21 = at(h+1, w), v22 = at(h+1, w+1);
    float sx = (v02 - v00) + 2.0f * (v12 - v10) + (v22 - v20);
    float sy = (v20 - v00) + 2.0f * (v21 - v01) + (v22 - v02);
    int id = (int)st[h * WW + w];
    int gy = h >> 3, i = h & 7, gx = w >> 3, j = w & 7;
    long row = (long)b * NN + gy * GG + gx;
    unsigned short* xr = X0 + row * KIM + i * 8 + j;
#pragma unroll
    for (int c = 0; c < 10; c++) xr[c * 64] = (id == c) ? 0x3F80u : 0u;
    xr[10 * 64] = f2b(sx);
    xr[11 * 64] = f2b(sy);
}

// ---------------- bf16 MFMA NT GEMM ----------------
template <int BM, int BN, int ACT>
__global__ __launch_bounds__(256) void gemm_bf16(
    const unsigned short* __restrict__ A, const unsigned short* __restrict__ W,
    const float* __restrict__ bias, const float* __restrict__ res,
    float* __restrict__ C, unsigned short* __restrict__ Cb,
    int K, long sA, long sW, long sC1, long sC2, int cdiv, int ldc, float scale)
{
    constexpr int WN = BN / 64;
    __shared__ __align__(16) unsigned short As[BM * 32];
    __shared__ __align__(16) unsigned short Bs[BN * 32];
    const int tid = threadIdx.x;
    const int w = tid >> 6, l = tid & 63;
    const int wm = w / WN, wn = w % WN;
    const int bz = blockIdx.z;
    const unsigned short* Ab = A + (long)bz * sA + (long)(blockIdx.y * BM) * K;
    const unsigned short* Wb = W + (long)bz * sW + (long)(blockIdx.x * BN) * K;
    const long offC = (long)(bz / cdiv) * sC1 + (long)(bz % cdiv) * sC2;

    const int rA  = l >> 2;
    const int swz = ((l & 3) ^ ((l >> 3) & 3)) * 8;

    f32x4 acc[4][4] = {};

    for (int k0 = 0; k0 < K; k0 += 32) {
#pragma unroll
        for (int c = 0; c < BM / 64; c++) {
            const int chunk = w * (BM / 64) + c;
            gload_lds16(Ab + (long)(chunk * 16 + rA) * K + k0 + swz, (char*)As + chunk * 1024);
        }
#pragma unroll
        for (int c = 0; c < BN / 64; c++) {
            const int chunk = w * (BN / 64) + c;
            gload_lds16(Wb + (long)(chunk * 16 + rA) * K + k0 + swz, (char*)Bs + chunk * 1024);
        }
        __syncthreads();
        short8 af[4], bfr[4];
#pragma unroll
        for (int m = 0; m < 4; m++) {
            const int row = wm * 64 + m * 16 + (l & 15);
            const int byte = row * 64 + (((l >> 4) ^ ((row >> 1) & 3)) << 4);
            af[m] = *(const short8*)((const char*)As + byte);
        }
#pragma unroll
        for (int n = 0; n < 4; n++) {
            const int row = wn * 64 + n * 16 + (l & 15);
            const int byte = row * 64 + (((l >> 4) ^ ((row >> 1) & 3)) << 4);
            bfr[n] = *(const short8*)((const char*)Bs + byte);
        }
#pragma unroll
        for (int m = 0; m < 4; m++)
#pragma unroll
            for (int n = 0; n < 4; n++)
                acc[m][n] = __builtin_amdgcn_mfma_f32_16x16x32_bf16(af[m], bfr[n], acc[m][n], 0, 0, 0);
        __syncthreads();
    }

    const int crow0 = blockIdx.y * BM + wm * 64;
    const int ccol0 = blockIdx.x * BN + wn * 64;
#pragma unroll
    for (int m = 0; m < 4; m++) {
#pragma unroll
        for (int n = 0; n < 4; n++) {
            const int row = crow0 + m * 16 + ((l >> 4) << 2);
            const int col = ccol0 + n * 16 + (l & 15);
#pragma unroll
            for (int r = 0; r < 4; r++) {
                float v = acc[m][n][r] * scale;
                if (bias) v += bias[col];
                if (ACT == 1) v = gelu_exact(v);
                const long idx = offC + (long)(row + r) * ldc + col;
                if (res) v += res[idx];
                if (C)  C[idx] = v;
                if (Cb) Cb[idx] = f2b(v);
            }
        }
    }
}

// ---------------- fp32 tile GEMM (slot loop) ----------------
template <int ACT>
__global__ __launch_bounds__(256) void gemm_nt(
    const float* __restrict__ A, const float* __restrict__ W,
    const float* __restrict__ bias, const float* __restrict__ res,
    float* __restrict__ C, int M, int N, int K,
    long sA, long sW, long sC1, long sC2, int cdiv, int ldc, float scale)
{
    const int bz = blockIdx.z;
    const float* Ab = A + (long)bz * sA;
    const float* Wb = W + (long)bz * sW;
    const long offC = (long)(bz / cdiv) * sC1 + (long)(bz % cdiv) * sC2;
    float* Cb = C + offC;
    const float* Rb = res ? res + offC : nullptr;

    __shared__ float As[16][68];
    __shared__ float Ws[16][68];

    const int tid = threadIdx.x;
    const int tx = tid & 15;
    const int ty = tid >> 4;
    const int row0 = blockIdx.y << 6;
    const int col0 = blockIdx.x << 6;

    float acc[4][4] = {};

    for (int k0 = 0; k0 < K; k0 += 16) {
#pragma unroll
        for (int i = 0; i < 4; i++) {
            const int idx = tid + (i << 8);
            const int m = idx >> 4;
            const int kk = idx & 15;
            As[kk][m] = Ab[(long)(row0 + m) * K + (k0 + kk)];
            Ws[kk][m] = Wb[(long)(col0 + m) * K + (k0 + kk)];
        }
        __syncthreads();
#pragma unroll
        for (int kk = 0; kk < 16; kk++) {
            const float4 a4 = *(const float4*)&As[kk][ty << 2];
            const float4 b4 = *(const float4*)&Ws[kk][tx << 2];
            const float a[4] = {a4.x, a4.y, a4.z, a4.w};
            const float b[4] = {b4.x, b4.y, b4.z, b4.w};
#pragma unroll
            for (int i = 0; i < 4; i++)
#pragma unroll
                for (int j = 0; j < 4; j++)
                    acc[i][j] = fmaf(a[i], b[j], acc[i][j]);
        }
        __syncthreads();
    }

    const int crow = row0 + (ty << 2);
    const int ccol = col0 + (tx << 2);
#pragma unroll
    for (int i = 0; i < 4; i++) {
#pragma unroll
        for (int j = 0; j < 4; j++) {
            float v = acc[i][j] * scale;
            if (bias) v += bias[ccol + j];
            if (ACT == 1) v = gelu_exact(v);
            if (Rb) v += Rb[(long)(crow + i) * ldc + (ccol + j)];
            Cb[(long)(crow + i) * ldc + (ccol + j)] = v;
        }
    }
}

// ---------------- LayerNorm (wave per row) ----------------
template <typename OT>
__global__ __launch_bounds__(256) void ln_rows(const float* __restrict__ X,
                                               OT* __restrict__ Y,
                                               const float* __restrict__ g,
                                               const float* __restrict__ b,
                                               int rows, int D) {
    int gtid = blockIdx.x * 256 + threadIdx.x;
    int row = gtid >> 6;
    int lane = gtid & 63;
    if (row >= rows) return;
    const float* x = X + (long)row * D;
    const int nv = D >> 6;
    float v[5];
    float s = 0.0f;
#pragma unroll 5
    for (int i = 0; i < nv; i++) { v[i] = x[lane + (i << 6)]; s += v[i]; }
#pragma unroll
    for (int o = 32; o; o >>= 1) s += __shfl_down(s, o);
    s = __shfl(s, 0);
    float mean = s / (float)D;
    float s2 = 0.0f;
#pragma unroll 5
    for (int i = 0; i < nv; i++) { float d = v[i] - mean; s2 += d * d; }
#pragma unroll
    for (int o = 32; o; o >>= 1) s2 += __shfl_down(s2, o);
    s2 = __shfl(s2, 0);
    float inv = rsqrtf(s2 / (float)D + 1e-5f);
    OT* y = Y + (long)row * D;
#pragma unroll 5
    for (int i = 0; i < nv; i++) {
        int d = lane + (i << 6);
        store_el(&y[d], (v[i] - mean) * inv * g[d] + b[d]);
    }
}

// ---------------- table-driven RoPE: QKVb -> Qr, Kr (bf16) ----------------
__global__ __launch_bounds__(256) void rope_qk(const unsigned short* __restrict__ QKVb,
                                               const float* __restrict__ cs,
                                               const float* __restrict__ sn,
                                               unsigned short* __restrict__ Qr,
                                               unsigned short* __restrict__ Kr) {
    const int rid = blockIdx.x * 256 + threadIdx.x;   // b*1024 + h*256 + n, < 65536
    const int n = rid & 255;
    const int h = (rid >> 8) & 3;
    const int b = rid >> 10;
    const unsigned short* src = QKVb + ((long)(b * 256 + n)) * 768 + h * 64;
    float cv[64], sv[64];
#pragma unroll
    for (int i = 0; i < 16; i++) {
        *(float4*)&cv[i * 4] = *(const float4*)(cs + n * 64 + i * 4);
        *(float4*)&sv[i * 4] = *(const float4*)(sn + n * 64 + i * 4);
    }
#pragma unroll
    for (int qk = 0; qk < 2; qk++) {
        const unsigned short* s0 = src + qk * 256;
        unsigned short* dst = (qk == 0 ? Qr : Kr) + (long)rid * 64;
        float x[64];
#pragma unroll
        for (int i = 0; i < 8; i++) {
            short8 v = *(const short8*)(s0 + i * 8);
#pragma unroll
            for (int j = 0; j < 8; j++) x[i * 8 + j] = b2f((unsigned short)v[j]);
        }
        unsigned short o[64];
#pragma unroll
        for (int d = 0; d < 64; d++) {
            const float rot = (d < 32) ? -x[2 * d + 1] : x[2 * (d - 32)];
            o[d] = f2b(x[d] * cv[d] + rot * sv[d]);
        }
#pragma unroll
        for (int i = 0; i < 8; i++)
            *(short8*)(dst + i * 8) = *(short8*)&o[i * 8];
    }
}

// ---------------- fused attention: one wg per (b,h) ----------------
// Swapped QK^T (S^T in regs), in-register softmax over keys, P via wave-private
// LDS repack (frag layout), PV with V^T staged in swizzled LDS. AO bf16 out.
__global__ __launch_bounds__(256, 1) void fused_attn(
    const unsigned short* __restrict__ Qr,
    const unsigned short* __restrict__ Kr,
    const unsigned short* __restrict__ QKVb,
    unsigned short* __restrict__ AOb)
{
    __shared__ __align__(16) char SL[49152];   // V^T 32KB + P 16KB
    const int h = blockIdx.x, b = blockIdx.y;
    const int tid = threadIdx.x;
    const int w = tid >> 6, l = tid & 63;
    const int gw = l >> 4, l15 = l & 15;
    const long bh = (long)b * 4 + h;
    const unsigned short* Qb = Qr + bh * NN * 64;
    const unsigned short* Kb = Kr + bh * NN * 64;

    // ---- stage V^T[d][n], swizzled: byte = d*512 + ((n>>3)^(d&15))*16 + (n&7)*2
    {
        const int n0 = (tid & 127) * 2;
        const int dh = tid >> 7;
        const unsigned short* v0p = QKVb + ((long)b * NN + n0) * 768 + h * 64 + 512 + dh * 32;
        const unsigned short* v1p = v0p + 768;
        unsigned short v0[32], v1[32];
#pragma unroll
        for (int i = 0; i < 4; i++) {
            *(short8*)&v0[i * 8] = *(const short8*)(v0p + i * 8);
            *(short8*)&v1[i * 8] = *(const short8*)(v1p + i * 8);
        }
#pragma unroll
        for (int i = 0; i < 32; i++) {
            const int d = dh * 32 + i;
            const unsigned val = (unsigned)v0[i] | ((unsigned)v1[i] << 16);
            *(unsigned*)(SL + d * 512 + (((n0 >> 3) ^ (d & 15)) << 4) + (n0 & 7) * 2) = val;
        }
    }
    __syncthreads();

    char* Pw = SL + 32768 + w * 4096;   // wave-private P scratch

#pragma unroll
    for (int p = 0; p < 2; p++) {
        const int mbase = w * 64 + p * 32;
        // ---- QK^T: S^T[key n][query m]  (A = K rows, B = Q rows)
        f32x4 accs[16][2] = {};
#pragma unroll
        for (int kk = 0; kk < 2; kk++) {
            short8 bq[2];
#pragma unroll
            for (int mf = 0; mf < 2; mf++)
                bq[mf] = *(const short8*)(Qb + ((mbase + mf * 16 + l15) << 6) + kk * 32 + gw * 8);
#pragma unroll
            for (int nf = 0; nf < 16; nf++) {
                const short8 ak = *(const short8*)(Kb + ((nf * 16 + l15) << 6) + kk * 32 + gw * 8);
#pragma unroll
                for (int mf = 0; mf < 2; mf++)
                    accs[nf][mf] = __builtin_amdgcn_mfma_f32_16x16x32_bf16(ak, bq[mf], accs[nf][mf], 0, 0, 0);
            }
        }
        // ---- softmax over keys (rows of S^T): in-lane + xor16/xor32
        float rs[2];
#pragma unroll
        for (int mf = 0; mf < 2; mf++) {
            float mx = -1e30f;
#pragma unroll
            for (int nf = 0; nf < 16; nf++)
#pragma unroll
                for (int r = 0; r < 4; r++) mx = fmaxf(mx, accs[nf][mf][r]);
            mx = fmaxf(mx, __shfl_xor(mx, 16));
            mx = fmaxf(mx, __shfl_xor(mx, 32));
            float sum = 0.0f;
#pragma unroll
            for (int nf = 0; nf < 16; nf++)
#pragma unroll
                for (int r = 0; r < 4; r++) {
                    const float e = expf((accs[nf][mf][r] - mx) * 0.125f);
                    accs[nf][mf][r] = e;
                    sum += e;
                }
            sum += __shfl_xor(sum, 16);
            sum += __shfl_xor(sum, 32);
            rs[mf] = 1.0f / sum;
        }
        // ---- PV: AO^T[d][m] accumulate; P repacked chunk-wise through LDS
        f32x4 acco[4][2] = {};
#pragma unroll
        for (int c = 0; c < 4; c++) {
            // pack this chunk's P (keys [c*64, c*64+64)) into frag layout
#pragma unroll
            for (int nfi = 0; nfi < 4; nfi++) {
                const int nf = c * 4 + nfi;
                const int kt = nf >> 1;
                const int gr = (nf & 1) * 2 + (gw >> 1);
                const int lr = l15 + 16 * gr;
                const int j0 = (gw & 1) * 4;
#pragma unroll
                for (int mf = 0; mf < 2; mf++) {
                    uint2 pk;
                    pk.x = (unsigned)f2b(accs[nf][mf][0] * rs[mf]) |
                           ((unsigned)f2b(accs[nf][mf][1] * rs[mf]) << 16);
                    pk.y = (unsigned)f2b(accs[nf][mf][2] * rs[mf]) |
                           ((unsigned)f2b(accs[nf][mf][3] * rs[mf]) << 16);
                    *(uint2*)(Pw + ((kt & 1) * 2 + mf) * 1024 + lr * 16 + j0 * 2) = pk;
                }
            }
#pragma unroll
            for (int kti = 0; kti < 2; kti++) {
                const int kt = c * 2 + kti;
                short8 vf[4];
#pragma unroll
                for (int df = 0; df < 4; df++) {
                    const int d = df * 16 + l15;
                    vf[df] = *(const short8*)(SL + d * 512 + (((kt * 4 + gw) ^ (d & 15)) << 4));
                }
#pragma unroll
                for (int mf = 0; mf < 2; mf++) {
                    const short8 pf = *(const short8*)(Pw + (kti * 2 + mf) * 1024 + l * 16);
#pragma unroll
                    for (int df = 0; df < 4; df++)
                        acco[df][mf] = __builtin_amdgcn_mfma_f32_16x16x32_bf16(vf[df], pf, acco[df][mf], 0, 0, 0);
                }
            }
        }
        // ---- epilogue: AO[m][h*64+d] bf16
#pragma unroll
        for (int df = 0; df < 4; df++)
#pragma unroll
            for (int mf = 0; mf < 2; mf++) {
                const int m = mbase + mf * 16 + l15;
                const int d = df * 16 + gw * 4;
                unsigned short o[4];
#pragma unroll
                for (int r = 0; r < 4; r++) o[r] = f2b(acco[df][mf][r]);
                *(uint2*)(AOb + ((long)(b * NN + m) * 256 + h * 64 + d)) = *(uint2*)o;
            }
    }
}

// ---------------- slot logits + softmax over slots ----------------
__global__ __launch_bounds__(256) void slot_logits(const float* __restrict__ Kin,
                                                   const float* __restrict__ Qs,
                                                   float* __restrict__ sattn,
                                                   float* __restrict__ sums) {
    const int b = blockIdx.x;
    const int chunk = blockIdx.y;
    __shared__ float qs[NSL][FD];
    __shared__ float colsum[NSL];
    const int tid = threadIdx.x;
    for (int i = tid; i < NSL * FD; i += 256) qs[i / FD][i % FD] = Qs[(long)b * NSL * FD + i];
    if (tid < NSL) colsum[tid] = 0.0f;
    __syncthreads();
    const int wv = tid >> 6, lane = tid & 63;
    float wsum[NSL] = {};
#pragma unroll
    for (int rr = 0; rr < 4; rr++) {
        const int r = chunk * 16 + wv * 4 + rr;
        const float* kr = Kin + ((long)b * NN + r) * FD;
        float acc[NSL] = {};
#pragma unroll
        for (int i = 0; i < 5; i++) {
            const int t = lane + (i << 6);
            const float kv = kr[t];
#pragma unroll
            for (int s = 0; s < NSL; s++) acc[s] = fmaf(kv, qs[s][t], acc[s]);
        }
#pragma unroll
        for (int s = 0; s < NSL; s++)
#pragma unroll
            for (int o = 32; o; o >>= 1) acc[s] += __shfl_down(acc[s], o);
        if (lane == 0) {
            const float scale = 0.055901699437494740f;  // 1/sqrt(320)
            float mx = -1e30f;
#pragma unroll
            for (int s = 0; s < NSL; s++) { acc[s] *= scale; mx = fmaxf(mx, acc[s]); }
            float e[NSL], sum = 0.0f;
#pragma unroll
            for (int s = 0; s < NSL; s++) { e[s] = expf(acc[s] - mx); sum += e[s]; }
            const float rsum = 1.0f / sum;
            float* outp = sattn + ((long)b * NN + r) * NSL;
#pragma unroll
            for (int s = 0; s < NSL; s++) {
                const float pp = e[s] * rsum;
                outp[s] = pp;
                wsum[s] += pp;
            }
        }
    }
    if (lane == 0) {
#pragma unroll
        for (int s = 0; s < NSL; s++) atomicAdd(&colsum[s], wsum[s]);
    }
    __syncthreads();
    if (tid < NSL) atomicAdd(&sums[b * NSL + tid], colsum[tid]);
}

// ---------------- slot updates ----------------
__global__ __launch_bounds__(256) void slot_updates(const float* __restrict__ sattn,
                                                    const float* __restrict__ sums,
                                                    const float* __restrict__ Vin,
                                                    float* __restrict__ Upd) {
    const int b = blockIdx.x;
    const int chunk = blockIdx.y;
    const int t = threadIdx.x;
    __shared__ float an[64][NSL];
    __shared__ float inv_s[NSL];
    if (t < NSL) inv_s[t] = 1.0f / (sums[b * NSL + t] + (float)NN * 1e-8f);
    __syncthreads();
    for (int i = t; i < 64 * NSL; i += 256) {
        const int s = i & 7;
        const int n = i >> 3;
        an[n][s] = (sattn[((long)b * NN + chunk * 64 + n) * NSL + s] + 1e-8f) * inv_s[s];
    }
    __syncthreads();
    float acc[NSL][2] = {};
    const float* vb = Vin + ((long)b * NN + chunk * 64) * FD;
    for (int n = 0; n < 64; n++) {
        const float v1 = vb[(long)n * FD + t];
        const float v2 = (t < 64) ? vb[(long)n * FD + 256 + t] : 0.0f;
#pragma unroll
        for (int s = 0; s < NSL; s++) {
            const float a = an[n][s];
            acc[s][0] = fmaf(a, v1, acc[s][0]);
            acc[s][1] = fmaf(a, v2, acc[s][1]);
        }
    }
    float* ub = Upd + (long)b * NSL * FD;
#pragma unroll
    for (int s = 0; s < NSL; s++) {
        atomicAdd(&ub[s * FD + t], acc[s][0]);
        if (t < 64) atomicAdd(&ub[s * FD + 256 + t], acc[s][1]);
    }
}

// ---------------- GRU elementwise ----------------
__global__ __launch_bounds__(256) void gru_elem(const float* __restrict__ GI,
                                                const float* __restrict__ GH,
                                                float* __restrict__ slots) {
    int idx = blockIdx.x * 256 + threadIdx.x;
    if (idx >= BB * NSL * FD) return;
    int r = idx / FD, f = idx % FD;
    const float* gi = GI + (long)r * 3 * FD;
    const float* gh = GH + (long)r * 3 * FD;
    float rr = sigm(gi[f] + gh[f]);
    float z = sigm(gi[FD + f] + gh[FD + f]);
    float nn = tanhf(gi[2 * FD + f] + rr * gh[2 * FD + f]);
    float hh = slots[idx];
    slots[idx] = (1.0f - z) * nn + z * hh;
}

// ---------------- output packing ----------------
__global__ __launch_bounds__(256) void write_out(const float* __restrict__ slots,
                                                 const float* __restrict__ sattn,
                                                 float* __restrict__ out) {
    int idx = blockIdx.x * 256 + threadIdx.x;
    const int SLOT_SZ = BB * NSL * FD;
    const int MASK_SZ = BB * NSL * NN;
    if (idx < SLOT_SZ) {
        out[idx] = slots[idx];
    } else if (idx < SLOT_SZ + MASK_SZ) {
        int i = idx - SLOT_SZ;
        int b = i >> 11;
        int s = (i >> 8) & 7;
        int n = i & 255;
        out[idx] = sattn[((long)b * NN + n) * NSL + s];
    }
}

// ---------------- host launcher ----------------
extern "C" void kernel_launch(void* const* d_in, const int* in_sizes, int n_in,
                              void* d_out, int out_size, void* d_ws, size_t ws_size,
                              hipStream_t stream) {
    const float* state    = (const float*)d_in[0];
    const float* conv_w   = (const float*)d_in[1];
    const float* conv_b   = (const float*)d_in[2];
    const float* mlp_ln_g = (const float*)d_in[3];
    const float* mlp_ln_b = (const float*)d_in[4];
    const float* mlp_w1   = (const float*)d_in[5];
    const float* mlp_b1   = (const float*)d_in[6];
    const float* mlp_w2   = (const float*)d_in[7];
    const float* mlp_b2   = (const float*)d_in[8];
    const float* qkv_w    = (const float*)d_in[9];
    const float* qkv_b    = (const float*)d_in[10];
    const float* proj_w   = (const float*)d_in[11];
    const float* proj_b   = (const float*)d_in[12];
    const float* ni_g     = (const float*)d_in[13];
    const float* ni_b     = (const float*)d_in[14];
    const float* ns_g     = (const float*)d_in[15];
    const float* ns_b     = (const float*)d_in[16];
    const float* nm_g     = (const float*)d_in[17];
    const float* nm_b     = (const float*)d_in[18];
    const float* q_w      = (const float*)d_in[19];
    const float* k_w      = (const float*)d_in[20];
    const float* v_w      = (const float*)d_in[21];
    const float* gru_wih  = (const float*)d_in[22];
    const float* gru_whh  = (const float*)d_in[23];
    const float* gru_bih  = (const float*)d_in[24];
    const float* gru_bhh  = (const float*)d_in[25];
    const float* smlp_w1  = (const float*)d_in[26];
    const float* smlp_b1  = (const float*)d_in[27];
    const float* smlp_w2  = (const float*)d_in[28];
    const float* smlp_b2  = (const float*)d_in[29];

    float* ws = (float*)d_ws;
    const int M = BB * NN;  // 16384
    typedef unsigned short u16;

    // ---- workspace layout ----
    // Region A: X0b (conv staging) -> Qr/Kr (roped, [bh][n][d])
    u16*   X0b  = (u16*)(ws + 0L);
    u16*   Qr   = (u16*)(ws + 0L);
    u16*   Kr   = (u16*)(ws + 2097152L);
    // Region B: X1 / XLNb / Hbufb -> QKVb
    float* X1   = ws + 6291456L;
    u16*   XLNb = (u16*)(ws + 10485760L);
    u16*   Hbufb= (u16*)(ws + 12582912L);
    u16*   QKVb = (u16*)(ws + 6291456L);
    // Region C: X2b
    u16*   X2b  = (u16*)(ws + 23068672L);
    // Region D: X2 fp32 -> Xnb
    float* X2   = ws + 31457280L;
    u16*   Xnb  = (u16*)(ws + 31457280L);
    // Region E: X3 -> slot buffers
    float* X3   = ws + 35651584L;
    float* Slots= ws + 35651584L;
    float* SLn  = ws + 35815424L;
    float* Qs   = ws + 35979264L;
    float* Satt = ws + 36143104L;
    float* Sums = ws + 36274176L;
    float* Upd  = ws + 36274688L;
    float* GI   = ws + 36438528L;
    float* GH   = ws + 36930048L;
    float* Mh   = ws + 37421568L;
    // Region F/G: Kin, Vin
    float* Kin  = ws + 39845888L;
    float* Vin  = ws + 45088768L;
    // Region H: AOb + bf16 weights (contiguous) + rope tables
    u16*   AOb    = (u16*)(ws + 50331648L);
    u16*   wb_all = (u16*)(ws + 52428800L);   // 884736 u16, contiguous:
    u16*   conv_wb= (u16*)(ws + 52428800L);
    u16*   mlp_w1b= (u16*)(ws + 52527104L);
    u16*   mlp_w2b= (u16*)(ws + 52592640L);
    u16*   qkv_wb = (u16*)(ws + 52658176L);
    u16*   proj_wb= (u16*)(ws + 52756480L);
    u16*   k_wb   = (u16*)(ws + 52789248L);
    u16*   v_wb   = (u16*)(ws + 52830208L);
    float* CS     = ws + 52871168L;
    float* SN     = ws + 52887552L;

    float* out = (float*)d_out;

    auto gemmA = [&](const u16* A, const u16* Wt, const float* bias, const float* res,
                     float* C, u16* Cb, int Mm, int Nn, int Kk, int batch,
                     long sA, long sW, long sC1, long sC2, int cdiv, int ldc,
                     float scale, int act) {
        dim3 grid(Nn / 128, Mm / 128, batch);
        if (act) gemm_bf16<128, 128, 1><<<grid, 256, 0, stream>>>(A, Wt, bias, res, C, Cb, Kk, sA, sW, sC1, sC2, cdiv, ldc, scale);
        else     gemm_bf16<128, 128, 0><<<grid, 256, 0, stream>>>(A, Wt, bias, res, C, Cb, Kk, sA, sW, sC1, sC2, cdiv, ldc, scale);
    };
    auto gemmB = [&](const u16* A, const u16* Wt, const float* bias, const float* res,
                     float* C, u16* Cb, int Mm, int Nn, int Kk, int batch,
                     long sA, long sW, long sC1, long sC2, int cdiv, int ldc,
                     float scale) {
        dim3 grid(Nn / 64, Mm / 256, batch);
        gemm_bf16<256, 64, 0><<<grid, 256, 0, stream>>>(A, Wt, bias, res, C, Cb, Kk, sA, sW, sC1, sC2, cdiv, ldc, scale);
    };
    auto gemmF = [&](const float* A, const float* Wt, const float* bias, const float* res,
                     float* C, int Mm, int Nn, int Kk, float scale, int act) {
        dim3 grid(Nn / 64, Mm / 64, 1);
        if (act) gemm_nt<1><<<grid, 256, 0, stream>>>(A, Wt, bias, res, C, Mm, Nn, Kk, 0, 0, 0, 0, 1, Nn, scale);
        else     gemm_nt<0><<<grid, 256, 0, stream>>>(A, Wt, bias, res, C, Mm, Nn, Kk, 0, 0, 0, 0, 1, Nn, scale);
    };

    // 0. weight conversions (one kernel) + rope tables
    cvt_weights<<<dim3(884736 / 256), 256, 0, stream>>>(conv_w, mlp_w1, mlp_w2, qkv_w,
                                                        proj_w, k_w, v_w, wb_all);
    rope_tab<<<dim3(16384 / 256), 256, 0, stream>>>(CS, SN);

    // 1. sobel + onehot + im2col (bf16)
    sobel_im2col<<<dim3((BB * HH * WW) / 256), 256, 0, stream>>>(state, X0b);
    // 2. patch conv GEMM -> X1 fp32
    gemmA(X0b, conv_wb, conv_b, nullptr, X1, nullptr, M, EE, KIM, 1, 0, 0, 0, 0, 1, EE, 1.0f, 0);
    // 3. LN -> bf16, MLP
    ln_rows<u16><<<dim3(M * 64 / 256), 256, 0, stream>>>(X1, XLNb, mlp_ln_g, mlp_ln_b, M, EE);
    gemmA(XLNb, mlp_w1b, mlp_b1, nullptr, nullptr, Hbufb, M, 2 * EE, EE, 1, 0, 0, 0, 0, 1, 2 * EE, 1.0f, 1);
    gemmA(Hbufb, mlp_w2b, mlp_b2, nullptr, X2, X2b, M, EE, 2 * EE, 1, 0, 0, 0, 0, 1, EE, 1.0f, 0);
    // 4. QKV (bf16 only) + table-driven rope
    gemmA(X2b, qkv_wb, qkv_b, nullptr, nullptr, QKVb, M, 3 * EE, EE, 1, 0, 0, 0, 0, 1, 3 * EE, 1.0f, 0);
    rope_qk<<<dim3(65536 / 256), 256, 0, stream>>>(QKVb, CS, SN, Qr, Kr);
    // 5. fused attention -> AOb
    fused_attn<<<dim3(NHEAD, BB), 256, 0, stream>>>(Qr, Kr, QKVb, AOb);
    // 6. proj + residual -> X3 fp32
    gemmA(AOb, proj_wb, proj_b, X2, X3, nullptr, M, EE, EE, 1, 0, 0, 0, 0, 1, EE, 1.0f, 0);
    // 7. LN ni -> bf16, k_in / v_in (fp32 out)
    ln_rows<u16><<<dim3(M * 64 / 256), 256, 0, stream>>>(X3, Xnb, ni_g, ni_b, M, EE);
    gemmB(Xnb, k_wb, nullptr, nullptr, Kin, nullptr, M, FD, EE, 1, 0, 0, 0, 0, 1, FD, 1.0f);
    gemmB(Xnb, v_wb, nullptr, nullptr, Vin, nullptr, M, FD, EE, 1, 0, 0, 0, 0, 1, FD, 1.0f);
    // 8. slot attention loop (fp32)
    hipMemsetAsync(Slots, 0, (size_t)BB * NSL * FD * sizeof(float), stream);
    const int SR = BB * NSL;  // 512
    for (int it = 0; it < 3; it++) {
        ln_rows<float><<<dim3(SR * 64 / 256), 256, 0, stream>>>(Slots, SLn, ns_g, ns_b, SR, FD);
        gemmF(SLn, q_w, nullptr, nullptr, Qs, SR, FD, FD, 1.0f, 0);
        hipMemsetAsync(Sums, 0, (size_t)BB * NSL * sizeof(float), stream);
        slot_logits<<<dim3(BB, 16), 256, 0, stream>>>(Kin, Qs, Satt, Sums);
        hipMemsetAsync(Upd, 0, (size_t)BB * NSL * FD * sizeof(float), stream);
        slot_updates<<<dim3(BB, 4), 256, 0, stream>>>(Satt, Sums, Vin, Upd);
        gemmF(Upd, gru_wih, gru_bih, nullptr, GI, SR, 3 * FD, FD, 1.0f, 0);
        gemmF(Slots, gru_whh, gru_bhh, nullptr, GH, SR, 3 * FD, FD, 1.0f, 0);
        gru_elem<<<dim3((SR * FD) / 256), 256, 0, stream>>>(GI, GH, Slots);
        ln_rows<float><<<dim3(SR * 64 / 256), 256, 0, stream>>>(Slots, SLn, nm_g, nm_b, SR, FD);
        gemmF(SLn, smlp_w1, smlp_b1, nullptr, Mh, SR, 2 * FD, FD, 1.0f, 1);
        gemmF(Mh, smlp_w2, smlp_b2, Slots, Slots, SR, FD, 2 * FD, 1.0f, 0);
    }
    // 9. outputs
    write_out<<<dim3((BB * NSL * FD + BB * NSL * NN + 255) / 256), 256, 0, stream>>>(Slots, Satt, out);
}

// Round 5
// 644.110 us; speedup vs baseline: 2.7687x; 1.3763x over previous
//
#include <hip/hip_runtime.h>
#include <math.h>

// ---------------- problem constants ----------------
#define BB   64
#define HH   128
#define WW   128
#define GG   16
#define NN   256     // G*G tokens
#define EE   256
#define FD   320
#define NSL  8       // slots
#define NHEAD 4
#define HD   64
#define KIM  768     // 12*8*8 im2col K

using short8 = __attribute__((ext_vector_type(8))) short;
using f32x4  = __attribute__((ext_vector_type(4))) float;

__device__ __forceinline__ float sigm(float x) { return 1.0f / (1.0f + expf(-x)); }
__device__ __forceinline__ float gelu_exact(float x) {
    return 0.5f * x * (1.0f + erff(x * 0.70710678118654752f));
}
// round-to-nearest-even f32 -> bf16
__device__ __forceinline__ unsigned short f2b(float x) {
    unsigned u = __float_as_uint(x);
    u += 0x7fffu + ((u >> 16) & 1u);
    return (unsigned short)(u >> 16);
}
__device__ __forceinline__ float b2f(unsigned short u) {
    return __uint_as_float(((unsigned)u) << 16);
}
__device__ __forceinline__ void gload_lds16(const void* g, void* lds) {
    __builtin_amdgcn_global_load_lds(
        (const __attribute__((address_space(1))) unsigned int*)g,
        (__attribute__((address_space(3))) unsigned int*)lds, 16, 0, 0);
}
__device__ __forceinline__ void store_el(float* p, float v) { *p = v; }
__device__ __forceinline__ void store_el(unsigned short* p, float v) { *p = f2b(v); }

// ---------------- all weight conversions in one kernel ----------------
__global__ __launch_bounds__(256) void cvt_weights(
    const float* __restrict__ w0, const float* __restrict__ w1,
    const float* __restrict__ w2, const float* __restrict__ w3,
    const float* __restrict__ w4, const float* __restrict__ w5,
    const float* __restrict__ w6, const float* __restrict__ w7,
    const float* __restrict__ w8, const float* __restrict__ w9,
    const float* __restrict__ w10, const float* __restrict__ w11,
    unsigned short* __restrict__ dst) {
    int i = blockIdx.x * 256 + threadIdx.x;   // < 2011136
    float v;
    if      (i <  196608) v = w0[i];
    else if (i <  327680) v = w1[i - 196608];
    else if (i <  458752) v = w2[i - 327680];
    else if (i <  655360) v = w3[i - 458752];
    else if (i <  720896) v = w4[i - 655360];
    else if (i <  802816) v = w5[i - 720896];
    else if (i <  884736) v = w6[i - 802816];
    else if (i <  987136) v = w7[i - 884736];
    else if (i < 1294336) v = w8[i - 987136];
    else if (i < 1601536) v = w9[i - 1294336];
    else if (i < 1806336) v = w10[i - 1601536];
    else                  v = w11[i - 1806336];
    dst[i] = f2b(v);
}

// ---------------- fp32 -> bf16 convert ----------------
__global__ __launch_bounds__(256) void cvt_bf16(const float* __restrict__ in,
                                                unsigned short* __restrict__ out, int n) {
    int i = blockIdx.x * 256 + threadIdx.x;
    if (i < n) out[i] = f2b(in[i]);
}

// ---------------- RoPE tables: cs/sn[n][d], n<256, d<64 ----------------
__global__ __launch_bounds__(256) void rope_tab(float* __restrict__ cs,
                                                float* __restrict__ sn) {
    int i = blockIdx.x * 256 + threadIdx.x;   // 16384
    int d = i & 63, n = i >> 6;
    int pos = (d < 32) ? (n >> 4) : (n & 15);
    int j = d & 31;
    float freq = powf(10000.0f, -(float)(j & 15) / 16.0f);
    float p = (float)pos * freq;
    float ang = (j < 16) ? sinf(p) : cosf(p);
    cs[i] = cosf(ang);
    sn[i] = sinf(ang);
}

// ---------------- Sobel + one-hot + im2col (bf16 out, exact) ----------------
__global__ __launch_bounds__(256) void sobel_im2col(const float* __restrict__ state,
                                                    unsigned short* __restrict__ X0) {
    int idx = blockIdx.x * 256 + threadIdx.x;
    if (idx >= BB * HH * WW) return;
    int w = idx % WW;
    int h = (idx / WW) % HH;
    int b = idx / (HH * WW);
    const float* st = state + (long)b * HH * WW;
    auto at = [&](int y, int x) {
        y = min(max(y, 0), HH - 1);
        x = min(max(x, 0), WW - 1);
        return st[y * WW + x];
    };
    float v00 = at(h-1, w-1), v01 = at(h-1, w), v02 = at(h-1, w+1);
    float v10 = at(h,   w-1),                  v12 = at(h,   w+1);
    float v20 = at(h+1, w-1), v21 = at(h+1, w), v22 = at(h+1, w+1);
    float sx = (v02 - v00) + 2.0f * (v12 - v10) + (v22 - v20);
    float sy = (v20 - v00) + 2.0f * (v21 - v01) + (v22 - v02);
    int id = (int)st[h * WW + w];
    int gy = h >> 3, i = h & 7, gx = w >> 3, j = w & 7;
    long row = (long)b * NN + gy * GG + gx;
    unsigned short* xr = X0 + row * KIM + i * 8 + j;
#pragma unroll
    for (int c = 0; c < 10; c++) xr[c * 64] = (id == c) ? 0x3F80u : 0u;
    xr[10 * 64] = f2b(sx);
    xr[11 * 64] = f2b(sy);
}

// ---------------- bf16 MFMA NT GEMM (big path) ----------------
template <int BM, int BN, int ACT>
__global__ __launch_bounds__(256) void gemm_bf16(
    const unsigned short* __restrict__ A, const unsigned short* __restrict__ W,
    const float* __restrict__ bias, const float* __restrict__ res,
    float* __restrict__ C, unsigned short* __restrict__ Cb,
    int K, long sA, long sW, long sC1, long sC2, int cdiv, int ldc, float scale)
{
    constexpr int WN = BN / 64;
    __shared__ __align__(16) unsigned short As[BM * 32];
    __shared__ __align__(16) unsigned short Bs[BN * 32];
    const int tid = threadIdx.x;
    const int w = tid >> 6, l = tid & 63;
    const int wm = w / WN, wn = w % WN;
    const int bz = blockIdx.z;
    const unsigned short* Ab = A + (long)bz * sA + (long)(blockIdx.y * BM) * K;
    const unsigned short* Wb = W + (long)bz * sW + (long)(blockIdx.x * BN) * K;
    const long offC = (long)(bz / cdiv) * sC1 + (long)(bz % cdiv) * sC2;

    const int rA  = l >> 2;
    const int swz = ((l & 3) ^ ((l >> 3) & 3)) * 8;

    f32x4 acc[4][4] = {};

    for (int k0 = 0; k0 < K; k0 += 32) {
#pragma unroll
        for (int c = 0; c < BM / 64; c++) {
            const int chunk = w * (BM / 64) + c;
            gload_lds16(Ab + (long)(chunk * 16 + rA) * K + k0 + swz, (char*)As + chunk * 1024);
        }
#pragma unroll
        for (int c = 0; c < BN / 64; c++) {
            const int chunk = w * (BN / 64) + c;
            gload_lds16(Wb + (long)(chunk * 16 + rA) * K + k0 + swz, (char*)Bs + chunk * 1024);
        }
        __syncthreads();
        short8 af[4], bfr[4];
#pragma unroll
        for (int m = 0; m < 4; m++) {
            const int row = wm * 64 + m * 16 + (l & 15);
            const int byte = row * 64 + (((l >> 4) ^ ((row >> 1) & 3)) << 4);
            af[m] = *(const short8*)((const char*)As + byte);
        }
#pragma unroll
        for (int n = 0; n < 4; n++) {
            const int row = wn * 64 + n * 16 + (l & 15);
            const int byte = row * 64 + (((l >> 4) ^ ((row >> 1) & 3)) << 4);
            bfr[n] = *(const short8*)((const char*)Bs + byte);
        }
#pragma unroll
        for (int m = 0; m < 4; m++)
#pragma unroll
            for (int n = 0; n < 4; n++)
                acc[m][n] = __builtin_amdgcn_mfma_f32_16x16x32_bf16(af[m], bfr[n], acc[m][n], 0, 0, 0);
        __syncthreads();
    }

    const int crow0 = blockIdx.y * BM + wm * 64;
    const int ccol0 = blockIdx.x * BN + wn * 64;
#pragma unroll
    for (int m = 0; m < 4; m++) {
#pragma unroll
        for (int n = 0; n < 4; n++) {
            const int row = crow0 + m * 16 + ((l >> 4) << 2);
            const int col = ccol0 + n * 16 + (l & 15);
#pragma unroll
            for (int r = 0; r < 4; r++) {
                float v = acc[m][n][r] * scale;
                if (bias) v += bias[col];
                if (ACT == 1) v = gelu_exact(v);
                const long idx = offC + (long)(row + r) * ldc + col;
                if (res) v += res[idx];
                if (C)  C[idx] = v;
                if (Cb) Cb[idx] = f2b(v);
            }
        }
    }
}

// ---------------- small bf16 MFMA NT GEMM (slot loop): 64x64 tile ----------------
// grid (N/64, M/64, batch). Wave w computes rows 0..63 x cols [w*16, w*16+16).
template <int ACT>
__global__ __launch_bounds__(256) void gemm_bf16_s(
    const unsigned short* __restrict__ A, const unsigned short* __restrict__ W,
    const float* __restrict__ bias0, const float* __restrict__ bias1,
    const float* __restrict__ res,
    float* __restrict__ C, unsigned short* __restrict__ Cb,
    int K, int N, long sA, long sW, long sC, float scale)
{
    __shared__ __align__(16) unsigned short As[64 * 32];
    __shared__ __align__(16) unsigned short Bs[64 * 32];
    const int tid = threadIdx.x;
    const int w = tid >> 6, l = tid & 63;
    const int gw = l >> 4, l15 = l & 15;
    const int bz = blockIdx.z;
    const unsigned short* Ab = A + (long)bz * sA + (long)(blockIdx.y * 64) * K;
    const unsigned short* Wb = W + (long)bz * sW + (long)(blockIdx.x * 64) * K;
    const float* bias = (bz == 0) ? bias0 : bias1;
    const long offC = (long)bz * sC;

    const int rA  = l >> 2;
    const int swz = ((l & 3) ^ ((l >> 3) & 3)) * 8;

    f32x4 acc[4] = {};

    for (int k0 = 0; k0 < K; k0 += 32) {
        gload_lds16(Ab + (long)(w * 16 + rA) * K + k0 + swz, (char*)As + w * 1024);
        gload_lds16(Wb + (long)(w * 16 + rA) * K + k0 + swz, (char*)Bs + w * 1024);
        __syncthreads();
        short8 af[4];
#pragma unroll
        for (int m = 0; m < 4; m++) {
            const int row = m * 16 + l15;
            af[m] = *(const short8*)((const char*)As + row * 64 + ((gw ^ ((row >> 1) & 3)) << 4));
        }
        const int brow = w * 16 + l15;
        const short8 bf = *(const short8*)((const char*)Bs + brow * 64 + ((gw ^ ((brow >> 1) & 3)) << 4));
#pragma unroll
        for (int m = 0; m < 4; m++)
            acc[m] = __builtin_amdgcn_mfma_f32_16x16x32_bf16(af[m], bf, acc[m], 0, 0, 0);
        __syncthreads();
    }

    const int col = blockIdx.x * 64 + w * 16 + l15;
    const int row0 = blockIdx.y * 64;
#pragma unroll
    for (int m = 0; m < 4; m++) {
        const int row = row0 + m * 16 + (gw << 2);
#pragma unroll
        for (int r = 0; r < 4; r++) {
            float v = acc[m][r] * scale;
            if (bias) v += bias[col];
            if (ACT == 1) v = gelu_exact(v);
            const long idx = offC + (long)(row + r) * N + col;
            if (res) v += res[idx];
            if (C)  C[idx] = v;
            if (Cb) Cb[idx] = f2b(v);
        }
    }
}

// ---------------- LayerNorm (wave per row) ----------------
template <typename OT>
__global__ __launch_bounds__(256) void ln_rows(const float* __restrict__ X,
                                               OT* __restrict__ Y,
                                               const float* __restrict__ g,
                                               const float* __restrict__ b,
                                               int rows, int D) {
    int gtid = blockIdx.x * 256 + threadIdx.x;
    int row = gtid >> 6;
    int lane = gtid & 63;
    if (row >= rows) return;
    const float* x = X + (long)row * D;
    const int nv = D >> 6;
    float v[5];
    float s = 0.0f;
#pragma unroll 5
    for (int i = 0; i < nv; i++) { v[i] = x[lane + (i << 6)]; s += v[i]; }
#pragma unroll
    for (int o = 32; o; o >>= 1) s += __shfl_down(s, o);
    s = __shfl(s, 0);
    float mean = s / (float)D;
    float s2 = 0.0f;
#pragma unroll 5
    for (int i = 0; i < nv; i++) { float d = v[i] - mean; s2 += d * d; }
#pragma unroll
    for (int o = 32; o; o >>= 1) s2 += __shfl_down(s2, o);
    s2 = __shfl(s2, 0);
    float inv = rsqrtf(s2 / (float)D + 1e-5f);
    OT* y = Y + (long)row * D;
#pragma unroll 5
    for (int i = 0; i < nv; i++) {
        int d = lane + (i << 6);
        store_el(&y[d], (v[i] - mean) * inv * g[d] + b[d]);
    }
}

// ---------------- fused GRU + LayerNorm(nm) (wave per row) ----------------
__global__ __launch_bounds__(256) void gru_ln(const float* __restrict__ GI,
                                              const float* __restrict__ GH,
                                              float* __restrict__ slots,
                                              const float* __restrict__ g,
                                              const float* __restrict__ b,
                                              unsigned short* __restrict__ SLnb) {
    int gtid = blockIdx.x * 256 + threadIdx.x;
    int row = gtid >> 6;        // < 512
    int lane = gtid & 63;
    const float* gi = GI + (long)row * 960;
    const float* gh = GH + (long)row * 960;
    float* sl = slots + (long)row * FD;
    float h[5];
    float s = 0.0f;
#pragma unroll
    for (int i = 0; i < 5; i++) {
        const int f = lane + (i << 6);
        const float rr = sigm(gi[f] + gh[f]);
        const float z  = sigm(gi[320 + f] + gh[320 + f]);
        const float nn = tanhf(gi[640 + f] + rr * gh[640 + f]);
        const float hn = (1.0f - z) * nn + z * sl[f];
        h[i] = hn;
        s += hn;
        sl[f] = hn;
    }
#pragma unroll
    for (int o = 32; o; o >>= 1) s += __shfl_down(s, o);
    s = __shfl(s, 0);
    const float mean = s * (1.0f / FD);
    float s2 = 0.0f;
#pragma unroll
    for (int i = 0; i < 5; i++) { const float d = h[i] - mean; s2 += d * d; }
#pragma unroll
    for (int o = 32; o; o >>= 1) s2 += __shfl_down(s2, o);
    s2 = __shfl(s2, 0);
    const float inv = rsqrtf(s2 * (1.0f / FD) + 1e-5f);
    unsigned short* y = SLnb + (long)row * FD;
#pragma unroll
    for (int i = 0; i < 5; i++) {
        const int f = lane + (i << 6);
        y[f] = f2b((h[i] - mean) * inv * g[f] + b[f]);
    }
}

// ---------------- table-driven RoPE: QKVb -> Qr, Kr (bf16) ----------------
__global__ __launch_bounds__(256) void rope_qk(const unsigned short* __restrict__ QKVb,
                                               const float* __restrict__ cs,
                                               const float* __restrict__ sn,
                                               unsigned short* __restrict__ Qr,
                                               unsigned short* __restrict__ Kr) {
    const int rid = blockIdx.x * 256 + threadIdx.x;   // b*1024 + h*256 + n
    const int n = rid & 255;
    const int h = (rid >> 8) & 3;
    const int b = rid >> 10;
    const unsigned short* src = QKVb + ((long)(b * 256 + n)) * 768 + h * 64;
    float cv[64], sv[64];
#pragma unroll
    for (int i = 0; i < 16; i++) {
        *(float4*)&cv[i * 4] = *(const float4*)(cs + n * 64 + i * 4);
        *(float4*)&sv[i * 4] = *(const float4*)(sn + n * 64 + i * 4);
    }
#pragma unroll
    for (int qk = 0; qk < 2; qk++) {
        const unsigned short* s0 = src + qk * 256;
        unsigned short* dst = (qk == 0 ? Qr : Kr) + (long)rid * 64;
        float x[64];
#pragma unroll
        for (int i = 0; i < 8; i++) {
            short8 v = *(const short8*)(s0 + i * 8);
#pragma unroll
            for (int j = 0; j < 8; j++) x[i * 8 + j] = b2f((unsigned short)v[j]);
        }
        unsigned short o[64];
#pragma unroll
        for (int d = 0; d < 64; d++) {
            const float rot = (d < 32) ? -x[2 * d + 1] : x[2 * (d - 32)];
            o[d] = f2b(x[d] * cv[d] + rot * sv[d]);
        }
#pragma unroll
        for (int i = 0; i < 8; i++)
            *(short8*)(dst + i * 8) = *(short8*)&o[i * 8];
    }
}

// ---------------- fused attention: one wg per (b,h) ----------------
__global__ __launch_bounds__(256, 1) void fused_attn(
    const unsigned short* __restrict__ Qr,
    const unsigned short* __restrict__ Kr,
    const unsigned short* __restrict__ QKVb,
    unsigned short* __restrict__ AOb)
{
    __shared__ __align__(16) char SL[49152];   // V^T 32KB + P 16KB
    const int h = blockIdx.x, b = blockIdx.y;
    const int tid = threadIdx.x;
    const int w = tid >> 6, l = tid & 63;
    const int gw = l >> 4, l15 = l & 15;
    const long bh = (long)b * 4 + h;
    const unsigned short* Qb = Qr + bh * NN * 64;
    const unsigned short* Kb = Kr + bh * NN * 64;

    {
        const int n0 = (tid & 127) * 2;
        const int dh = tid >> 7;
        const unsigned short* v0p = QKVb + ((long)b * NN + n0) * 768 + h * 64 + 512 + dh * 32;
        const unsigned short* v1p = v0p + 768;
        unsigned short v0[32], v1[32];
#pragma unroll
        for (int i = 0; i < 4; i++) {
            *(short8*)&v0[i * 8] = *(const short8*)(v0p + i * 8);
            *(short8*)&v1[i * 8] = *(const short8*)(v1p + i * 8);
        }
#pragma unroll
        for (int i = 0; i < 32; i++) {
            const int d = dh * 32 + i;
            const unsigned val = (unsigned)v0[i] | ((unsigned)v1[i] << 16);
            *(unsigned*)(SL + d * 512 + (((n0 >> 3) ^ (d & 15)) << 4) + (n0 & 7) * 2) = val;
        }
    }
    __syncthreads();

    char* Pw = SL + 32768 + w * 4096;

#pragma unroll
    for (int p = 0; p < 2; p++) {
        const int mbase = w * 64 + p * 32;
        f32x4 accs[16][2] = {};
#pragma unroll
        for (int kk = 0; kk < 2; kk++) {
            short8 bq[2];
#pragma unroll
            for (int mf = 0; mf < 2; mf++)
                bq[mf] = *(const short8*)(Qb + ((mbase + mf * 16 + l15) << 6) + kk * 32 + gw * 8);
#pragma unroll
            for (int nf = 0; nf < 16; nf++) {
                const short8 ak = *(const short8*)(Kb + ((nf * 16 + l15) << 6) + kk * 32 + gw * 8);
#pragma unroll
                for (int mf = 0; mf < 2; mf++)
                    accs[nf][mf] = __builtin_amdgcn_mfma_f32_16x16x32_bf16(ak, bq[mf], accs[nf][mf], 0, 0, 0);
            }
        }
        float rs[2];
#pragma unroll
        for (int mf = 0; mf < 2; mf++) {
            float mx = -1e30f;
#pragma unroll
            for (int nf = 0; nf < 16; nf++)
#pragma unroll
                for (int r = 0; r < 4; r++) mx = fmaxf(mx, accs[nf][mf][r]);
            mx = fmaxf(mx, __shfl_xor(mx, 16));
            mx = fmaxf(mx, __shfl_xor(mx, 32));
            float sum = 0.0f;
#pragma unroll
            for (int nf = 0; nf < 16; nf++)
#pragma unroll
                for (int r = 0; r < 4; r++) {
                    const float e = expf((accs[nf][mf][r] - mx) * 0.125f);
                    accs[nf][mf][r] = e;
                    sum += e;
                }
            sum += __shfl_xor(sum, 16);
            sum += __shfl_xor(sum, 32);
            rs[mf] = 1.0f / sum;
        }
        f32x4 acco[4][2] = {};
#pragma unroll
        for (int c = 0; c < 4; c++) {
#pragma unroll
            for (int nfi = 0; nfi < 4; nfi++) {
                const int nf = c * 4 + nfi;
                const int kt = nf >> 1;
                const int gr = (nf & 1) * 2 + (gw >> 1);
                const int lr = l15 + 16 * gr;
                const int j0 = (gw & 1) * 4;
#pragma unroll
                for (int mf = 0; mf < 2; mf++) {
                    uint2 pk;
                    pk.x = (unsigned)f2b(accs[nf][mf][0] * rs[mf]) |
                           ((unsigned)f2b(accs[nf][mf][1] * rs[mf]) << 16);
                    pk.y = (unsigned)f2b(accs[nf][mf][2] * rs[mf]) |
                           ((unsigned)f2b(accs[nf][mf][3] * rs[mf]) << 16);
                    *(uint2*)(Pw + ((kt & 1) * 2 + mf) * 1024 + lr * 16 + j0 * 2) = pk;
                }
            }
#pragma unroll
            for (int kti = 0; kti < 2; kti++) {
                const int kt = c * 2 + kti;
                short8 vf[4];
#pragma unroll
                for (int df = 0; df < 4; df++) {
                    const int d = df * 16 + l15;
                    vf[df] = *(const short8*)(SL + d * 512 + (((kt * 4 + gw) ^ (d & 15)) << 4));
                }
#pragma unroll
                for (int mf = 0; mf < 2; mf++) {
                    const short8 pf = *(const short8*)(Pw + (kti * 2 + mf) * 1024 + l * 16);
#pragma unroll
                    for (int df = 0; df < 4; df++)
                        acco[df][mf] = __builtin_amdgcn_mfma_f32_16x16x32_bf16(vf[df], pf, acco[df][mf], 0, 0, 0);
                }
            }
        }
#pragma unroll
        for (int df = 0; df < 4; df++)
#pragma unroll
            for (int mf = 0; mf < 2; mf++) {
                const int m = mbase + mf * 16 + l15;
                const int d = df * 16 + gw * 4;
                unsigned short o[4];
#pragma unroll
                for (int r = 0; r < 4; r++) o[r] = f2b(acco[df][mf][r]);
                *(uint2*)(AOb + ((long)(b * NN + m) * 256 + h * 64 + d)) = *(uint2*)o;
            }
    }
}

// ---------------- slot logits + softmax over slots ----------------
__global__ __launch_bounds__(256) void slot_logits(const float* __restrict__ Kin,
                                                   const float* __restrict__ Qs,
                                                   float* __restrict__ sattn,
                                                   float* __restrict__ sums) {
    const int b = blockIdx.x;
    const int chunk = blockIdx.y;
    __shared__ float qs[NSL][FD];
    __shared__ float colsum[NSL];
    const int tid = threadIdx.x;
    for (int i = tid; i < NSL * FD; i += 256) qs[i / FD][i % FD] = Qs[(long)b * NSL * FD + i];
    if (tid < NSL) colsum[tid] = 0.0f;
    __syncthreads();
    const int wv = tid >> 6, lane = tid & 63;
    float wsum[NSL] = {};
#pragma unroll
    for (int rr = 0; rr < 4; rr++) {
        const int r = chunk * 16 + wv * 4 + rr;
        const float* kr = Kin + ((long)b * NN + r) * FD;
        float acc[NSL] = {};
#pragma unroll
        for (int i = 0; i < 5; i++) {
            const int t = lane + (i << 6);
            const float kv = kr[t];
#pragma unroll
            for (int s = 0; s < NSL; s++) acc[s] = fmaf(kv, qs[s][t], acc[s]);
        }
#pragma unroll
        for (int s = 0; s < NSL; s++)
#pragma unroll
            for (int o = 32; o; o >>= 1) acc[s] += __shfl_down(acc[s], o);
        if (lane == 0) {
            const float scale = 0.055901699437494740f;  // 1/sqrt(320)
            float mx = -1e30f;
#pragma unroll
            for (int s = 0; s < NSL; s++) { acc[s] *= scale; mx = fmaxf(mx, acc[s]); }
            float e[NSL], sum = 0.0f;
#pragma unroll
            for (int s = 0; s < NSL; s++) { e[s] = expf(acc[s] - mx); sum += e[s]; }
            const float rsum = 1.0f / sum;
            float* outp = sattn + ((long)b * NN + r) * NSL;
#pragma unroll
            for (int s = 0; s < NSL; s++) {
                const float pp = e[s] * rsum;
                outp[s] = pp;
                wsum[s] += pp;
            }
        }
    }
    if (lane == 0) {
#pragma unroll
        for (int s = 0; s < NSL; s++) atomicAdd(&colsum[s], wsum[s]);
    }
    __syncthreads();
    if (tid < NSL) atomicAdd(&sums[b * NSL + tid], colsum[tid]);
}

// ---------------- slot updates ----------------
__global__ __launch_bounds__(256) void slot_updates(const float* __restrict__ sattn,
                                                    const float* __restrict__ sums,
                                                    const float* __restrict__ Vin,
                                                    float* __restrict__ Upd) {
    const int b = blockIdx.x;
    const int chunk = blockIdx.y;
    const int t = threadIdx.x;
    __shared__ float an[64][NSL];
    __shared__ float inv_s[NSL];
    if (t < NSL) inv_s[t] = 1.0f / (sums[b * NSL + t] + (float)NN * 1e-8f);
    __syncthreads();
    for (int i = t; i < 64 * NSL; i += 256) {
        const int s = i & 7;
        const int n = i >> 3;
        an[n][s] = (sattn[((long)b * NN + chunk * 64 + n) * NSL + s] + 1e-8f) * inv_s[s];
    }
    __syncthreads();
    float acc[NSL][2] = {};
    const float* vb = Vin + ((long)b * NN + chunk * 64) * FD;
    for (int n = 0; n < 64; n++) {
        const float v1 = vb[(long)n * FD + t];
        const float v2 = (t < 64) ? vb[(long)n * FD + 256 + t] : 0.0f;
#pragma unroll
        for (int s = 0; s < NSL; s++) {
            const float a = an[n][s];
            acc[s][0] = fmaf(a, v1, acc[s][0]);
            acc[s][1] = fmaf(a, v2, acc[s][1]);
        }
    }
    float* ub = Upd + (long)b * NSL * FD;
#pragma unroll
    for (int s = 0; s < NSL; s++) {
        atomicAdd(&ub[s * FD + t], acc[s][0]);
        if (t < 64) atomicAdd(&ub[s * FD + 256 + t], acc[s][1]);
    }
}

// ---------------- output packing ----------------
__global__ __launch_bounds__(256) void write_out(const float* __restrict__ slots,
                                                 const float* __restrict__ sattn,
                                                 float* __restrict__ out) {
    int idx = blockIdx.x * 256 + threadIdx.x;
    const int SLOT_SZ = BB * NSL * FD;
    const int MASK_SZ = BB * NSL * NN;
    if (idx < SLOT_SZ) {
        out[idx] = slots[idx];
    } else if (idx < SLOT_SZ + MASK_SZ) {
        int i = idx - SLOT_SZ;
        int b = i >> 11;
        int s = (i >> 8) & 7;
        int n = i & 255;
        out[idx] = sattn[((long)b * NN + n) * NSL + s];
    }
}

// ---------------- host launcher ----------------
extern "C" void kernel_launch(void* const* d_in, const int* in_sizes, int n_in,
                              void* d_out, int out_size, void* d_ws, size_t ws_size,
                              hipStream_t stream) {
    const float* state    = (const float*)d_in[0];
    const float* conv_w   = (const float*)d_in[1];
    const float* conv_b   = (const float*)d_in[2];
    const float* mlp_ln_g = (const float*)d_in[3];
    const float* mlp_ln_b = (const float*)d_in[4];
    const float* mlp_w1   = (const float*)d_in[5];
    const float* mlp_b1   = (const float*)d_in[6];
    const float* mlp_w2   = (const float*)d_in[7];
    const float* mlp_b2   = (const float*)d_in[8];
    const float* qkv_w    = (const float*)d_in[9];
    const float* qkv_b    = (const float*)d_in[10];
    const float* proj_w   = (const float*)d_in[11];
    const float* proj_b   = (const float*)d_in[12];
    const float* ni_g     = (const float*)d_in[13];
    const float* ni_b     = (const float*)d_in[14];
    const float* ns_g     = (const float*)d_in[15];
    const float* ns_b     = (const float*)d_in[16];
    const float* nm_g     = (const float*)d_in[17];
    const float* nm_b     = (const float*)d_in[18];
    const float* q_w      = (const float*)d_in[19];
    const float* k_w      = (const float*)d_in[20];
    const float* v_w      = (const float*)d_in[21];
    const float* gru_wih  = (const float*)d_in[22];
    const float* gru_whh  = (const float*)d_in[23];
    const float* gru_bih  = (const float*)d_in[24];
    const float* gru_bhh  = (const float*)d_in[25];
    const float* smlp_w1  = (const float*)d_in[26];
    const float* smlp_b1  = (const float*)d_in[27];
    const float* smlp_w2  = (const float*)d_in[28];
    const float* smlp_b2  = (const float*)d_in[29];

    float* ws = (float*)d_ws;
    const int M = BB * NN;  // 16384
    typedef unsigned short u16;

    // ---- workspace layout (float offsets) ----
    u16*   X0b  = (u16*)(ws + 0L);
    u16*   Qr   = (u16*)(ws + 0L);
    u16*   Kr   = (u16*)(ws + 2097152L);
    float* X1   = ws + 6291456L;
    u16*   XLNb = (u16*)(ws + 10485760L);
    u16*   Hbufb= (u16*)(ws + 12582912L);
    u16*   QKVb = (u16*)(ws + 6291456L);
    u16*   X2b  = (u16*)(ws + 23068672L);
    float* X2   = ws + 31457280L;
    u16*   Xnb  = (u16*)(ws + 31457280L);
    float* X3   = ws + 35651584L;
    float* Slots= ws + 35651584L;     // 163840
    float* Qs   = ws + 35979264L;     // 163840
    float* Satt = ws + 36143104L;     // 131072
    float* Sums = ws + 36274176L;     // 512
    float* Upd  = ws + 36274688L;     // 163840
    float* GI   = ws + 36438528L;     // 491520
    float* GH   = ws + 36930048L;     // 491520
    u16*   SLnb = (u16*)(ws + 37421568L);  // 163840 u16
    u16*   Updb = (u16*)(ws + 37503488L);  // 163840 u16
    u16*   Slotsb=(u16*)(ws + 37585408L);  // 163840 u16 (contig after Updb)
    u16*   Mhb  = (u16*)(ws + 37667328L);  // 327680 u16
    float* Kin  = ws + 39845888L;
    float* Vin  = ws + 45088768L;
    u16*   AOb    = (u16*)(ws + 50331648L);
    u16*   wb     = (u16*)(ws + 52428800L);   // 2011136 u16 contiguous
    u16*   conv_wb= wb + 0;
    u16*   mlp_w1b= wb + 196608;
    u16*   mlp_w2b= wb + 327680;
    u16*   qkv_wb = wb + 458752;
    u16*   proj_wb= wb + 655360;
    u16*   k_wb   = wb + 720896;
    u16*   v_wb   = wb + 802816;
    u16*   q_wb   = wb + 884736;
    u16*   wihb   = wb + 987136;
    u16*   whhb   = wb + 1294336;
    u16*   smlp1b = wb + 1601536;
    u16*   smlp2b = wb + 1806336;
    float* CS     = ws + 53434368L;
    float* SN     = ws + 53450752L;

    float* out = (float*)d_out;

    auto gemmA = [&](const u16* A, const u16* Wt, const float* bias, const float* res,
                     float* C, u16* Cb, int Mm, int Nn, int Kk, int batch,
                     long sA, long sW, long sC1, long sC2, int cdiv, int ldc,
                     float scale, int act) {
        dim3 grid(Nn / 128, Mm / 128, batch);
        if (act) gemm_bf16<128, 128, 1><<<grid, 256, 0, stream>>>(A, Wt, bias, res, C, Cb, Kk, sA, sW, sC1, sC2, cdiv, ldc, scale);
        else     gemm_bf16<128, 128, 0><<<grid, 256, 0, stream>>>(A, Wt, bias, res, C, Cb, Kk, sA, sW, sC1, sC2, cdiv, ldc, scale);
    };
    auto gemmB = [&](const u16* A, const u16* Wt, float* C, int Mm, int Nn, int Kk) {
        dim3 grid(Nn / 64, Mm / 256, 1);
        gemm_bf16<256, 64, 0><<<grid, 256, 0, stream>>>(A, Wt, nullptr, nullptr, C, nullptr, Kk, 0, 0, 0, 0, 1, Nn, 1.0f);
    };
    auto gemmS = [&](const u16* A, const u16* Wt, const float* b0, const float* b1,
                     const float* res, float* C, u16* Cb, int Mm, int Nn, int Kk,
                     int batch, long sA, long sW, long sC, int act) {
        dim3 grid(Nn / 64, Mm / 64, batch);
        if (act) gemm_bf16_s<1><<<grid, 256, 0, stream>>>(A, Wt, b0, b1, res, C, Cb, Kk, Nn, sA, sW, sC, 1.0f);
        else     gemm_bf16_s<0><<<grid, 256, 0, stream>>>(A, Wt, b0, b1, res, C, Cb, Kk, Nn, sA, sW, sC, 1.0f);
    };

    // 0. weight conversions + rope tables
    cvt_weights<<<dim3(2011136 / 256), 256, 0, stream>>>(conv_w, mlp_w1, mlp_w2, qkv_w,
                                                         proj_w, k_w, v_w, q_w,
                                                         gru_wih, gru_whh, smlp_w1, smlp_w2, wb);
    rope_tab<<<dim3(16384 / 256), 256, 0, stream>>>(CS, SN);

    // 1. sobel + onehot + im2col (bf16)
    sobel_im2col<<<dim3((BB * HH * WW) / 256), 256, 0, stream>>>(state, X0b);
    // 2. patch conv GEMM -> X1 fp32
    gemmA(X0b, conv_wb, conv_b, nullptr, X1, nullptr, M, EE, KIM, 1, 0, 0, 0, 0, 1, EE, 1.0f, 0);
    // 3. LN -> bf16, MLP
    ln_rows<u16><<<dim3(M * 64 / 256), 256, 0, stream>>>(X1, XLNb, mlp_ln_g, mlp_ln_b, M, EE);
    gemmA(XLNb, mlp_w1b, mlp_b1, nullptr, nullptr, Hbufb, M, 2 * EE, EE, 1, 0, 0, 0, 0, 1, 2 * EE, 1.0f, 1);
    gemmA(Hbufb, mlp_w2b, mlp_b2, nullptr, X2, X2b, M, EE, 2 * EE, 1, 0, 0, 0, 0, 1, EE, 1.0f, 0);
    // 4. QKV + table rope
    gemmA(X2b, qkv_wb, qkv_b, nullptr, nullptr, QKVb, M, 3 * EE, EE, 1, 0, 0, 0, 0, 1, 3 * EE, 1.0f, 0);
    rope_qk<<<dim3(65536 / 256), 256, 0, stream>>>(QKVb, CS, SN, Qr, Kr);
    // 5. fused attention
    fused_attn<<<dim3(NHEAD, BB), 256, 0, stream>>>(Qr, Kr, QKVb, AOb);
    // 6. proj + residual -> X3 fp32
    gemmA(AOb, proj_wb, proj_b, X2, X3, nullptr, M, EE, EE, 1, 0, 0, 0, 0, 1, EE, 1.0f, 0);
    // 7. LN ni -> bf16, k_in / v_in
    ln_rows<u16><<<dim3(M * 64 / 256), 256, 0, stream>>>(X3, Xnb, ni_g, ni_b, M, EE);
    gemmB(Xnb, k_wb, Kin, M, FD, EE);
    gemmB(Xnb, v_wb, Vin, M, FD, EE);
    // 8. slot attention loop (bf16 MFMA GEMMs)
    hipMemsetAsync(Slots, 0, (size_t)BB * NSL * FD * sizeof(float), stream);
    hipMemsetAsync(Slotsb, 0, (size_t)BB * NSL * FD * sizeof(u16), stream);
    for (int it = 0; it < 3; it++) {
        ln_rows<u16><<<dim3(512 * 64 / 256), 256, 0, stream>>>(Slots, SLnb, ns_g, ns_b, 512, FD);
        gemmS(SLnb, q_wb, nullptr, nullptr, nullptr, Qs, nullptr, 512, FD, FD, 1, 0, 0, 0, 0);
        hipMemsetAsync(Sums, 0, (size_t)BB * NSL * sizeof(float), stream);
        slot_logits<<<dim3(BB, 16), 256, 0, stream>>>(Kin, Qs, Satt, Sums);
        hipMemsetAsync(Upd, 0, (size_t)BB * NSL * FD * sizeof(float), stream);
        slot_updates<<<dim3(BB, 4), 256, 0, stream>>>(Satt, Sums, Vin, Upd);
        cvt_bf16<<<dim3(163840 / 256), 256, 0, stream>>>(Upd, Updb, 163840);
        // GI = Updb@wih + bih ; GH = Slotsb@whh + bhh  (one launch, z=2)
        gemmS(Updb, wihb, gru_bih, gru_bhh, nullptr, GI, nullptr, 512, 960, FD,
              2, 163840, 307200, 491520, 0);
        gru_ln<<<dim3(512 * 64 / 256), 256, 0, stream>>>(GI, GH, Slots, nm_g, nm_b, SLnb);
        gemmS(SLnb, smlp1b, smlp_b1, nullptr, nullptr, nullptr, Mhb, 512, 2 * FD, FD, 1, 0, 0, 0, 1);
        gemmS(Mhb, smlp2b, smlp_b2, nullptr, Slots, Slots, Slotsb, 512, FD, 2 * FD, 1, 0, 0, 0, 0);
    }
    // 9. outputs
    write_out<<<dim3((BB * NSL * FD + BB * NSL * NN + 255) / 256), 256, 0, stream>>>(Slots, Satt, out);
}